// Round 1
// baseline (4965.810 us; speedup 1.0000x reference)
//
#include <hip/hip_runtime.h>
#include <math.h>

#define TSEQ 1024
#define CD   768
#define HN   12
#define DD   64

// workspace float offsets
#define OFF_QKVG   0          // 1024*3072
#define OFF_QHT    3145728    // 12*64*1024
#define OFF_KHT    3932160
#define OFF_GHT    4718592
#define OFF_G2     5505024    // 12*1024
#define OFF_Y      5517312    // 1024*768
#define OFF_CONSTS 6303744    // 12*20 + 1

// consts per head (stride 20): [0]=lam*dp_scale/6.4, [1]=(1-lam)*logk_scale,
// [2]=clip(beta)/2, [3]=out_scale, [4..11]=1/(4*tau), [12..19]=log(w+1e-12)
// alpha at [240]

__global__ __launch_bounds__(64) void prep_kernel(
    const float* __restrict__ lam_p, const float* __restrict__ log_tau,
    const float* __restrict__ logit_w, const float* __restrict__ beta,
    const float* __restrict__ out_scale, const float* __restrict__ dp_scale,
    const float* __restrict__ logk_scale, const float* __restrict__ dt_logit,
    float* __restrict__ consts) {
  int h = threadIdx.x;
  if (h == 0) {
    float dt = 1.0f / (1.0f + __expf(-dt_logit[0]));
    consts[12 * 20] = 0.1f * dt;  // ESR_ALPHA * dt
  }
  if (h < HN) {
    float lam = lam_p[0];
    float* c = consts + h * 20;
    c[0] = lam * dp_scale[h] * (1.0f / 6.4f);  // sqrt(64)*0.8 = 6.4
    c[1] = (1.0f - lam) * logk_scale[h];
    float b = fminf(fmaxf(beta[h], 0.5f), 2.5f);
    c[2] = 0.5f * b;
    c[3] = out_scale[h];
    float m = -1e30f;
    float lw[8];
    for (int t = 0; t < 8; t++) { lw[t] = logit_w[h * 8 + t]; m = fmaxf(m, lw[t]); }
    float s = 0.f;
    float e[8];
    for (int t = 0; t < 8; t++) { e[t] = __expf(lw[t] - m); s += e[t]; }
    for (int t = 0; t < 8; t++) {
      float w = e[t] / s;
      c[12 + t] = __logf(w + 1e-12f);
      float tau = fmaxf(__expf(log_tau[h * 8 + t]), 1e-6f);
      c[4 + t] = 1.0f / (4.0f * tau);
    }
  }
}

// C[M][N] = A[M][K] @ B[N][K]^T, all row-major, fp32. 64x64 tiles, kstep 32.
__global__ __launch_bounds__(256) void gemm_abT(
    const float* __restrict__ A, const float* __restrict__ B,
    float* __restrict__ Cm, int M, int N, int K) {
  __shared__ __align__(16) float AsT[32][68];
  __shared__ __align__(16) float BsT[32][68];
  int t = threadIdx.x;
  int tx = t & 15, ty = t >> 4;
  int n0 = blockIdx.x * 64, m0 = blockIdx.y * 64;
  float acc[4][4] = {};
  for (int k0 = 0; k0 < K; k0 += 32) {
    __syncthreads();
#pragma unroll
    for (int rep = 0; rep < 8; rep++) {
      int idx = rep * 256 + t;
      int r = idx >> 5, kk = idx & 31;
      AsT[kk][r] = A[(m0 + r) * K + k0 + kk];
      BsT[kk][r] = B[(n0 + r) * K + k0 + kk];
    }
    __syncthreads();
#pragma unroll
    for (int kk = 0; kk < 32; kk++) {
      float4 a4 = *(const float4*)&AsT[kk][4 * ty];
      float4 b4 = *(const float4*)&BsT[kk][4 * tx];
      acc[0][0] += a4.x * b4.x; acc[0][1] += a4.x * b4.y; acc[0][2] += a4.x * b4.z; acc[0][3] += a4.x * b4.w;
      acc[1][0] += a4.y * b4.x; acc[1][1] += a4.y * b4.y; acc[1][2] += a4.y * b4.z; acc[1][3] += a4.y * b4.w;
      acc[2][0] += a4.z * b4.x; acc[2][1] += a4.z * b4.y; acc[2][2] += a4.z * b4.z; acc[2][3] += a4.z * b4.w;
      acc[3][0] += a4.w * b4.x; acc[3][1] += a4.w * b4.y; acc[3][2] += a4.w * b4.z; acc[3][3] += a4.w * b4.w;
    }
  }
#pragma unroll
  for (int i = 0; i < 4; i++) {
    float4 o = make_float4(acc[i][0], acc[i][1], acc[i][2], acc[i][3]);
    *(float4*)&Cm[(m0 + 4 * ty + i) * N + n0 + 4 * tx] = o;
  }
}

// Extract q,k,g heads from qkvg, rmsnorm g, write d-major transposed [H][D][T];
// also g2[h][t] = ||g_norm||^2.
__global__ __launch_bounds__(256) void pack_kernel(
    const float* __restrict__ qkvg, const float* __restrict__ g_norm_w,
    float* __restrict__ qhT, float* __restrict__ khT,
    float* __restrict__ ghT, float* __restrict__ g2) {
  int h = blockIdx.y;
  int t0 = blockIdx.x * 64;
  int t = threadIdx.x;
  __shared__ float tile[64][65];
  __shared__ float gw[64];
  __shared__ float part1[64][4], part2[64][4];
  __shared__ float rr[64];
  if (t < 64) gw[t] = g_norm_w[t];
  const int offs[3] = {0, CD, 3 * CD};        // q, k, g column offsets in qkvg
  float* const outs[3] = {qhT, khT, ghT};
  for (int a = 0; a < 3; a++) {
    __syncthreads();
#pragma unroll
    for (int rep = 0; rep < 16; rep++) {
      int idx = rep * 256 + t;
      int r = idx >> 6, d = idx & 63;
      tile[r][d] = qkvg[(t0 + r) * 3072 + offs[a] + h * 64 + d];
    }
    __syncthreads();
    if (a == 2) {
      int row = t & 63, seg = t >> 6;
      float s1 = 0.f, s2 = 0.f;
      for (int d = seg * 16; d < seg * 16 + 16; d++) {
        float g = tile[row][d], w = gw[d];
        s1 += g * g;
        s2 += g * g * w * w;
      }
      part1[row][seg] = s1; part2[row][seg] = s2;
      __syncthreads();
      if (t < 64) {
        float a1 = part1[t][0] + part1[t][1] + part1[t][2] + part1[t][3];
        float a2 = part2[t][0] + part2[t][1] + part2[t][2] + part2[t][3];
        float rms = rsqrtf(a1 * (1.0f / 64.0f) + 1e-6f);
        rr[t] = rms;
        g2[h * TSEQ + t0 + t] = rms * rms * a2;
      }
      __syncthreads();
    }
    float* outp = outs[a];
#pragma unroll
    for (int rep = 0; rep < 16; rep++) {
      int idx = rep * 256 + t;
      int d = idx >> 6, tc = idx & 63;
      float v = tile[tc][d];
      if (a == 2) v *= rr[tc] * gw[d];
      outp[(h * 64 + d) * TSEQ + t0 + tc] = v;
    }
  }
}

// Flash-style fused scores+softmax+PV with analytic reversibilization.
// Block = 256 threads handles (head h, 32 rows i0..i0+31); j-tiles of 64.
__global__ __launch_bounds__(256) void flash_kernel(
    const float* __restrict__ qhT, const float* __restrict__ khT,
    const float* __restrict__ ghT, const float* __restrict__ g2,
    const float* __restrict__ qkvg, const float* __restrict__ consts,
    float* __restrict__ y) {
  int h = blockIdx.y;
  int it = (int)gridDim.x - 1 - (int)blockIdx.x;  // heavy blocks first
  int i0 = it * 32;
  int t = threadIdx.x;
  int tx = t & 15, ty = t >> 4;

  __shared__ __align__(16) float qsT[64][34];    // [kk][r]
  __shared__ __align__(16) float gisT[64][34];
  __shared__ __align__(16) float kvT[64 * 68];   // K^T [kk][c] in score phase, V [jj][d] in O phase
  __shared__ __align__(16) float gjsT[64][68];
  __shared__ float ps[32][65];
  __shared__ float g2i[32], g2j[64], ls[32], pdiag[32];

  const float* ch = consts + h * 20;
  float dpc = ch[0], lkc = ch[1], bh2 = ch[2], osc = ch[3];
  float inv4tau[8], logw[8];
#pragma unroll
  for (int tt = 0; tt < 8; tt++) { inv4tau[tt] = ch[4 + tt]; logw[tt] = ch[12 + tt]; }
  float alpha = consts[240];

#pragma unroll
  for (int rep = 0; rep < 8; rep++) {
    int idx = rep * 256 + t;
    int kk = idx >> 5, r = idx & 31;
    qsT[kk][r] = qhT[(h * 64 + kk) * TSEQ + i0 + r];
    gisT[kk][r] = ghT[(h * 64 + kk) * TSEQ + i0 + r];
  }
  if (t < 32) { g2i[t] = g2[h * TSEQ + i0 + t]; ls[t] = 0.f; pdiag[t] = 0.f; }

  float O[2][4] = {};

  int njt = it / 2 + 1;  // j-tiles of 64 needed to cover j <= i0+31
  for (int jt = 0; jt < njt; jt++) {
    int j0 = jt * 64;
    __syncthreads();
#pragma unroll
    for (int rep = 0; rep < 16; rep++) {
      int idx = rep * 256 + t;
      int kk = idx >> 6, c = idx & 63;
      kvT[kk * 68 + c] = khT[(h * 64 + kk) * TSEQ + j0 + c];
      gjsT[kk][c] = ghT[(h * 64 + kk) * TSEQ + j0 + c];
    }
    if (t < 64) g2j[t] = g2[h * TSEQ + j0 + t];
    __syncthreads();

    // score dots: rows r = 2ty+{0,1}, cols c = 4tx+{0..3}
    float aqk[2][4] = {}, agg[2][4] = {};
#pragma unroll
    for (int kk = 0; kk < 64; kk++) {
      float2 aq = *(const float2*)&qsT[kk][2 * ty];
      float2 ag = *(const float2*)&gisT[kk][2 * ty];
      float4 bk = *(const float4*)&kvT[kk * 68 + 4 * tx];
      float4 bg = *(const float4*)&gjsT[kk][4 * tx];
      aqk[0][0] += aq.x * bk.x; aqk[0][1] += aq.x * bk.y; aqk[0][2] += aq.x * bk.z; aqk[0][3] += aq.x * bk.w;
      aqk[1][0] += aq.y * bk.x; aqk[1][1] += aq.y * bk.y; aqk[1][2] += aq.y * bk.z; aqk[1][3] += aq.y * bk.w;
      agg[0][0] += ag.x * bg.x; agg[0][1] += ag.x * bg.y; agg[0][2] += ag.x * bg.z; agg[0][3] += ag.x * bg.w;
      agg[1][0] += ag.y * bg.x; agg[1][1] += ag.y * bg.y; agg[1][2] += ag.y * bg.z; agg[1][3] += ag.y * bg.w;
    }

    // blended -> p = exp(blended); range analysis: |blended| < ~7 so no max-shift needed
#pragma unroll
    for (int i2 = 0; i2 < 2; i2++) {
      int r = 2 * ty + i2;
      int gi = i0 + r;
      float g2iv = g2i[r];
#pragma unroll
      for (int j4 = 0; j4 < 4; j4++) {
        int c = 4 * tx + j4;
        int gj = j0 + c;
        float s = fmaxf(g2iv + g2j[c] - 2.0f * agg[i2][j4], 0.0f);
        float se = 0.f;
#pragma unroll
        for (int tt = 0; tt < 8; tt++) {
          se += __expf(-bh2 * __logf(1.0f + s * inv4tau[tt]) + logw[tt]);
        }
        float lse = __logf(se + 1e-30f);
        float b = dpc * aqk[i2][j4] + lkc * lse;
        float p = (gj <= gi) ? __expf(b) : 0.0f;
        ps[r][c] = p;
        if (gj == gi) pdiag[r] = p;
      }
    }
    __syncthreads();

    // row sums of this tile; stage V into kvT (K no longer needed)
    if (t < 32) {
      float lsum = 0.f;
      for (int jj = 0; jj < 64; jj++) lsum += ps[t][jj];
      ls[t] += lsum;
    }
#pragma unroll
    for (int rep = 0; rep < 16; rep++) {
      int idx = rep * 256 + t;
      int jj = idx >> 6, d = idx & 63;
      kvT[jj * 68 + d] = qkvg[(j0 + jj) * 3072 + 2 * CD + h * 64 + d];
    }
    __syncthreads();

    // O += P_tile @ V_tile : rows 2ty+{0,1}, dims 4tx+{0..3}
#pragma unroll
    for (int jj = 0; jj < 64; jj++) {
      float p0 = ps[2 * ty][jj];
      float p1 = ps[2 * ty + 1][jj];
      float4 v4 = *(const float4*)&kvT[jj * 68 + 4 * tx];
      O[0][0] += p0 * v4.x; O[0][1] += p0 * v4.y; O[0][2] += p0 * v4.z; O[0][3] += p0 * v4.w;
      O[1][0] += p1 * v4.x; O[1][1] += p1 * v4.y; O[1][2] += p1 * v4.z; O[1][3] += p1 * v4.w;
    }
  }

  // finalize: y_i = osc*(c1*(P@v)_i + c2*v_i) with c1,c2 from P_ii (analytic P_rev)
#pragma unroll
  for (int i2 = 0; i2 < 2; i2++) {
    int r = 2 * ty + i2;
    int gi = i0 + r;
    float l = fmaxf(ls[r], 1e-12f);
    float Pii = pdiag[r] / l;
    float inv1p = 1.0f / (1.0f + Pii);
    float c1 = (1.0f - alpha) + alpha * inv1p;
    float c2 = alpha * Pii * inv1p;
    float invl = 1.0f / l;
    float4 vi = *(const float4*)&qkvg[gi * 3072 + 2 * CD + h * 64 + 4 * tx];
    float4 o;
    o.x = osc * (c1 * O[i2][0] * invl + c2 * vi.x);
    o.y = osc * (c1 * O[i2][1] * invl + c2 * vi.y);
    o.z = osc * (c1 * O[i2][2] * invl + c2 * vi.z);
    o.w = osc * (c1 * O[i2][3] * invl + c2 * vi.w);
    *(float4*)&y[gi * CD + h * 64 + 4 * tx] = o;
  }
}

extern "C" void kernel_launch(void* const* d_in, const int* in_sizes, int n_in,
                              void* d_out, int out_size, void* d_ws, size_t ws_size,
                              hipStream_t stream) {
  (void)in_sizes; (void)n_in; (void)out_size; (void)ws_size;
  const float* x          = (const float*)d_in[0];
  const float* W_qkvg     = (const float*)d_in[1];
  const float* W_out      = (const float*)d_in[2];
  const float* lam        = (const float*)d_in[3];
  const float* log_tau    = (const float*)d_in[4];
  const float* logit_w    = (const float*)d_in[5];
  const float* beta       = (const float*)d_in[6];
  const float* out_scale  = (const float*)d_in[7];
  const float* dp_scale   = (const float*)d_in[8];
  const float* logk_scale = (const float*)d_in[9];
  const float* dt_logit   = (const float*)d_in[10];
  const float* g_norm_w   = (const float*)d_in[11];
  float* ws = (float*)d_ws;
  float* qkvg   = ws + OFF_QKVG;
  float* qhT    = ws + OFF_QHT;
  float* khT    = ws + OFF_KHT;
  float* ghT    = ws + OFF_GHT;
  float* g2     = ws + OFF_G2;
  float* y      = ws + OFF_Y;
  float* consts = ws + OFF_CONSTS;
  float* out = (float*)d_out;

  prep_kernel<<<dim3(1), dim3(64), 0, stream>>>(lam, log_tau, logit_w, beta,
                                                out_scale, dp_scale, logk_scale,
                                                dt_logit, consts);
  gemm_abT<<<dim3(48, 16), dim3(256), 0, stream>>>(x, W_qkvg, qkvg, 1024, 3072, 768);
  pack_kernel<<<dim3(16, 12), dim3(256), 0, stream>>>(qkvg, g_norm_w, qhT, khT, ghT, g2);
  flash_kernel<<<dim3(32, 12), dim3(256), 0, stream>>>(qhT, khT, ghT, g2, qkvg, consts, y);
  gemm_abT<<<dim3(12, 16), dim3(256), 0, stream>>>(y, W_out, out, 1024, 768, 768);
}

// Round 2
// 415.283 us; speedup vs baseline: 11.9576x; 11.9576x over previous
//
#include <hip/hip_runtime.h>
#include <math.h>

#define TSEQ 1024
#define CD   768
#define HN   12
#define DD   64

// workspace float offsets
#define OFF_QKVG   0          // 1024*3072
#define OFF_QHT    3145728    // 12*64*1024
#define OFF_KHT    3932160
#define OFF_GHT    4718592
#define OFF_G2     5505024    // 12*1024
#define OFF_Y      5517312    // 1024*768
#define OFF_CONSTS 6303744    // 12*20 + 1

// consts per head (stride 20): [0]=lam*dp_scale/6.4, [1]=(1-lam)*logk_scale,
// [2]=clip(beta)/2, [3]=out_scale, [4..11]=1/(4*tau), [12..19]=log2(w+1e-12)
// alpha at [240]

__global__ __launch_bounds__(64) void prep_kernel(
    const float* __restrict__ lam_p, const float* __restrict__ log_tau,
    const float* __restrict__ logit_w, const float* __restrict__ beta,
    const float* __restrict__ out_scale, const float* __restrict__ dp_scale,
    const float* __restrict__ logk_scale, const float* __restrict__ dt_logit,
    float* __restrict__ consts) {
  int h = threadIdx.x;
  if (h == 0) {
    float dt = 1.0f / (1.0f + __expf(-dt_logit[0]));
    consts[12 * 20] = 0.1f * dt;  // ESR_ALPHA * dt
  }
  if (h < HN) {
    float lam = lam_p[0];
    float* c = consts + h * 20;
    c[0] = lam * dp_scale[h] * (1.0f / 6.4f);  // sqrt(64)*0.8 = 6.4
    c[1] = (1.0f - lam) * logk_scale[h];
    float b = fminf(fmaxf(beta[h], 0.5f), 2.5f);
    c[2] = 0.5f * b;
    c[3] = out_scale[h];
    float m = -1e30f;
    float lw[8];
    for (int t = 0; t < 8; t++) { lw[t] = logit_w[h * 8 + t]; m = fmaxf(m, lw[t]); }
    float s = 0.f;
    float e[8];
    for (int t = 0; t < 8; t++) { e[t] = __expf(lw[t] - m); s += e[t]; }
    for (int t = 0; t < 8; t++) {
      float w = e[t] / s;
      c[12 + t] = log2f(w + 1e-12f);     // log2 domain
      float tau = fmaxf(__expf(log_tau[h * 8 + t]), 1e-6f);
      c[4 + t] = 1.0f / (4.0f * tau);
    }
  }
}

// C[M][N] = A[M][K] @ B[N][K]^T, all row-major, fp32. 64x64 tiles, kstep 32.
__global__ __launch_bounds__(256) void gemm_abT(
    const float* __restrict__ A, const float* __restrict__ B,
    float* __restrict__ Cm, int M, int N, int K) {
  __shared__ __align__(16) float AsT[32][68];
  __shared__ __align__(16) float BsT[32][68];
  int t = threadIdx.x;
  int tx = t & 15, ty = t >> 4;
  int n0 = blockIdx.x * 64, m0 = blockIdx.y * 64;
  float acc[4][4] = {};
  for (int k0 = 0; k0 < K; k0 += 32) {
    __syncthreads();
#pragma unroll 4
    for (int rep = 0; rep < 8; rep++) {
      int idx = rep * 256 + t;
      int r = idx >> 5, kk = idx & 31;
      AsT[kk][r] = A[(m0 + r) * K + k0 + kk];
      BsT[kk][r] = B[(n0 + r) * K + k0 + kk];
    }
    __syncthreads();
#pragma unroll 8
    for (int kk = 0; kk < 32; kk++) {
      float4 a4 = *(const float4*)&AsT[kk][4 * ty];
      float4 b4 = *(const float4*)&BsT[kk][4 * tx];
      acc[0][0] += a4.x * b4.x; acc[0][1] += a4.x * b4.y; acc[0][2] += a4.x * b4.z; acc[0][3] += a4.x * b4.w;
      acc[1][0] += a4.y * b4.x; acc[1][1] += a4.y * b4.y; acc[1][2] += a4.y * b4.z; acc[1][3] += a4.y * b4.w;
      acc[2][0] += a4.z * b4.x; acc[2][1] += a4.z * b4.y; acc[2][2] += a4.z * b4.z; acc[2][3] += a4.z * b4.w;
      acc[3][0] += a4.w * b4.x; acc[3][1] += a4.w * b4.y; acc[3][2] += a4.w * b4.z; acc[3][3] += a4.w * b4.w;
    }
  }
#pragma unroll
  for (int i = 0; i < 4; i++) {
    float4 o = make_float4(acc[i][0], acc[i][1], acc[i][2], acc[i][3]);
    *(float4*)&Cm[(m0 + 4 * ty + i) * N + n0 + 4 * tx] = o;
  }
}

// Extract q,k,g heads from qkvg, rmsnorm g, write d-major transposed [H][D][T];
// also g2[h][t] = ||g_norm||^2.
__global__ __launch_bounds__(256) void pack_kernel(
    const float* __restrict__ qkvg, const float* __restrict__ g_norm_w,
    float* __restrict__ qhT, float* __restrict__ khT,
    float* __restrict__ ghT, float* __restrict__ g2) {
  int h = blockIdx.y;
  int t0 = blockIdx.x * 64;
  int t = threadIdx.x;
  __shared__ float tile[64][65];
  __shared__ float gw[64];
  __shared__ float part1[64][4], part2[64][4];
  __shared__ float rr[64];
  if (t < 64) gw[t] = g_norm_w[t];
  const int offs[3] = {0, CD, 3 * CD};        // q, k, g column offsets in qkvg
  float* const outs[3] = {qhT, khT, ghT};
  for (int a = 0; a < 3; a++) {
    __syncthreads();
#pragma unroll 4
    for (int rep = 0; rep < 16; rep++) {
      int idx = rep * 256 + t;
      int r = idx >> 6, d = idx & 63;
      tile[r][d] = qkvg[(t0 + r) * 3072 + offs[a] + h * 64 + d];
    }
    __syncthreads();
    if (a == 2) {
      int row = t & 63, seg = t >> 6;
      float s1 = 0.f, s2 = 0.f;
      for (int d = seg * 16; d < seg * 16 + 16; d++) {
        float g = tile[row][d], w = gw[d];
        s1 += g * g;
        s2 += g * g * w * w;
      }
      part1[row][seg] = s1; part2[row][seg] = s2;
      __syncthreads();
      if (t < 64) {
        float a1 = part1[t][0] + part1[t][1] + part1[t][2] + part1[t][3];
        float a2 = part2[t][0] + part2[t][1] + part2[t][2] + part2[t][3];
        float rms = rsqrtf(a1 * (1.0f / 64.0f) + 1e-6f);
        rr[t] = rms;
        g2[h * TSEQ + t0 + t] = rms * rms * a2;
      }
      __syncthreads();
    }
    float* outp = outs[a];
#pragma unroll 4
    for (int rep = 0; rep < 16; rep++) {
      int idx = rep * 256 + t;
      int d = idx >> 6, tc = idx & 63;
      float v = tile[tc][d];
      if (a == 2) v *= rr[tc] * gw[d];
      outp[(h * 64 + d) * TSEQ + t0 + tc] = v;
    }
  }
}

// Flash-style fused scores+softmax+PV with analytic reversibilization.
// Block = 256 threads handles (head h, 32 rows i0..i0+31); j-tiles of 64.
__global__ __launch_bounds__(256, 2) void flash_kernel(
    const float* __restrict__ qhT, const float* __restrict__ khT,
    const float* __restrict__ ghT, const float* __restrict__ g2,
    const float* __restrict__ qkvg, const float* __restrict__ consts,
    float* __restrict__ y) {
  int h = blockIdx.y;
  int it = (int)gridDim.x - 1 - (int)blockIdx.x;  // heavy blocks first
  int i0 = it * 32;
  int t = threadIdx.x;
  int tx = t & 15, ty = t >> 4;

  __shared__ __align__(16) float qsT[64][34];    // [kk][r]
  __shared__ __align__(16) float gisT[64][34];
  __shared__ __align__(16) float kvT[64 * 68];   // K^T [kk][c] in score phase, V [jj][d] in O phase
  __shared__ __align__(16) float gjsT[64][68];
  __shared__ float ps[32][65];
  __shared__ float g2i[32], g2j[64], ls[32], pdiag[32];

  const float* ch = consts + h * 20;
  float dpc = ch[0] * 1.44269504089f;  // exp2-domain dot-product coeff
  float lkc = ch[1];                   // ln2*log2e == 1: logK coeff unchanged
  float bh2 = ch[2], osc = ch[3];
  float inv4tau[8], logw[8];
#pragma unroll
  for (int tt = 0; tt < 8; tt++) { inv4tau[tt] = ch[4 + tt]; logw[tt] = ch[12 + tt]; }
  float alpha = consts[240];

#pragma unroll 4
  for (int rep = 0; rep < 8; rep++) {
    int idx = rep * 256 + t;
    int kk = idx >> 5, r = idx & 31;
    qsT[kk][r] = qhT[(h * 64 + kk) * TSEQ + i0 + r];
    gisT[kk][r] = ghT[(h * 64 + kk) * TSEQ + i0 + r];
  }
  if (t < 32) { g2i[t] = g2[h * TSEQ + i0 + t]; ls[t] = 0.f; pdiag[t] = 0.f; }

  float O[2][4] = {};

  int njt = it / 2 + 1;  // j-tiles of 64 needed to cover j <= i0+31
  for (int jt = 0; jt < njt; jt++) {
    int j0 = jt * 64;
    __syncthreads();
#pragma unroll 4
    for (int rep = 0; rep < 16; rep++) {
      int idx = rep * 256 + t;
      int kk = idx >> 6, c = idx & 63;
      kvT[kk * 68 + c] = khT[(h * 64 + kk) * TSEQ + j0 + c];
      gjsT[kk][c] = ghT[(h * 64 + kk) * TSEQ + j0 + c];
    }
    if (t < 64) g2j[t] = g2[h * TSEQ + j0 + t];
    __syncthreads();

    // score dots: rows r = 2ty+{0,1}, cols c = 4tx+{0..3}
    float aqk[2][4] = {}, agg[2][4] = {};
#pragma unroll 8
    for (int kk = 0; kk < 64; kk++) {
      float2 aq = *(const float2*)&qsT[kk][2 * ty];
      float2 ag = *(const float2*)&gisT[kk][2 * ty];
      float4 bk = *(const float4*)&kvT[kk * 68 + 4 * tx];
      float4 bg = *(const float4*)&gjsT[kk][4 * tx];
      aqk[0][0] += aq.x * bk.x; aqk[0][1] += aq.x * bk.y; aqk[0][2] += aq.x * bk.z; aqk[0][3] += aq.x * bk.w;
      aqk[1][0] += aq.y * bk.x; aqk[1][1] += aq.y * bk.y; aqk[1][2] += aq.y * bk.z; aqk[1][3] += aq.y * bk.w;
      agg[0][0] += ag.x * bg.x; agg[0][1] += ag.x * bg.y; agg[0][2] += ag.x * bg.z; agg[0][3] += ag.x * bg.w;
      agg[1][0] += ag.y * bg.x; agg[1][1] += ag.y * bg.y; agg[1][2] += ag.y * bg.z; agg[1][3] += ag.y * bg.w;
    }

    // blended -> p = exp2(b2); range analysis: |b2| < ~10 so no max-shift needed
#pragma unroll
    for (int i2 = 0; i2 < 2; i2++) {
      int r = 2 * ty + i2;
      int gi = i0 + r;
      float g2iv = g2i[r];
#pragma unroll
      for (int j4 = 0; j4 < 4; j4++) {
        int c = 4 * tx + j4;
        int gj = j0 + c;
        float s = fmaxf(g2iv + g2j[c] - 2.0f * agg[i2][j4], 0.0f);
        float se = 0.f;
#pragma unroll
        for (int tt = 0; tt < 8; tt++) {
          float lv = __builtin_amdgcn_logf(fmaf(s, inv4tau[tt], 1.0f));  // log2
          se += __builtin_amdgcn_exp2f(fmaf(-bh2, lv, logw[tt]));
        }
        float lse = __builtin_amdgcn_logf(se + 1e-30f);  // log2(se)
        float b = fmaf(dpc, aqk[i2][j4], lkc * lse);
        float p = (gj <= gi) ? __builtin_amdgcn_exp2f(b) : 0.0f;
        ps[r][c] = p;
        if (gj == gi) pdiag[r] = p;
      }
    }
    __syncthreads();

    // row sums of this tile; stage V into kvT (K no longer needed)
    if (t < 32) {
      float lsum = 0.f;
#pragma unroll 8
      for (int jj = 0; jj < 64; jj++) lsum += ps[t][jj];
      ls[t] += lsum;
    }
#pragma unroll 4
    for (int rep = 0; rep < 16; rep++) {
      int idx = rep * 256 + t;
      int jj = idx >> 6, d = idx & 63;
      kvT[jj * 68 + d] = qkvg[(j0 + jj) * 3072 + 2 * CD + h * 64 + d];
    }
    __syncthreads();

    // O += P_tile @ V_tile : rows 2ty+{0,1}, dims 4tx+{0..3}
#pragma unroll 8
    for (int jj = 0; jj < 64; jj++) {
      float p0 = ps[2 * ty][jj];
      float p1 = ps[2 * ty + 1][jj];
      float4 v4 = *(const float4*)&kvT[jj * 68 + 4 * tx];
      O[0][0] += p0 * v4.x; O[0][1] += p0 * v4.y; O[0][2] += p0 * v4.z; O[0][3] += p0 * v4.w;
      O[1][0] += p1 * v4.x; O[1][1] += p1 * v4.y; O[1][2] += p1 * v4.z; O[1][3] += p1 * v4.w;
    }
  }

  // finalize: y_i = osc*(c1*(P@v)_i + c2*v_i) with c1,c2 from P_ii (analytic P_rev)
#pragma unroll
  for (int i2 = 0; i2 < 2; i2++) {
    int r = 2 * ty + i2;
    int gi = i0 + r;
    float l = fmaxf(ls[r], 1e-12f);
    float Pii = pdiag[r] / l;
    float inv1p = 1.0f / (1.0f + Pii);
    float c1 = (1.0f - alpha) + alpha * inv1p;
    float c2 = alpha * Pii * inv1p;
    float invl = 1.0f / l;
    float4 vi = *(const float4*)&qkvg[gi * 3072 + 2 * CD + h * 64 + 4 * tx];
    float4 o;
    o.x = osc * (c1 * O[i2][0] * invl + c2 * vi.x);
    o.y = osc * (c1 * O[i2][1] * invl + c2 * vi.y);
    o.z = osc * (c1 * O[i2][2] * invl + c2 * vi.z);
    o.w = osc * (c1 * O[i2][3] * invl + c2 * vi.w);
    *(float4*)&y[gi * CD + h * 64 + 4 * tx] = o;
  }
}

extern "C" void kernel_launch(void* const* d_in, const int* in_sizes, int n_in,
                              void* d_out, int out_size, void* d_ws, size_t ws_size,
                              hipStream_t stream) {
  (void)in_sizes; (void)n_in; (void)out_size; (void)ws_size;
  const float* x          = (const float*)d_in[0];
  const float* W_qkvg     = (const float*)d_in[1];
  const float* W_out      = (const float*)d_in[2];
  const float* lam        = (const float*)d_in[3];
  const float* log_tau    = (const float*)d_in[4];
  const float* logit_w    = (const float*)d_in[5];
  const float* beta       = (const float*)d_in[6];
  const float* out_scale  = (const float*)d_in[7];
  const float* dp_scale   = (const float*)d_in[8];
  const float* logk_scale = (const float*)d_in[9];
  const float* dt_logit   = (const float*)d_in[10];
  const float* g_norm_w   = (const float*)d_in[11];
  float* ws = (float*)d_ws;
  float* qkvg   = ws + OFF_QKVG;
  float* qhT    = ws + OFF_QHT;
  float* khT    = ws + OFF_KHT;
  float* ghT    = ws + OFF_GHT;
  float* g2     = ws + OFF_G2;
  float* y      = ws + OFF_Y;
  float* consts = ws + OFF_CONSTS;
  float* out = (float*)d_out;

  prep_kernel<<<dim3(1), dim3(64), 0, stream>>>(lam, log_tau, logit_w, beta,
                                                out_scale, dp_scale, logk_scale,
                                                dt_logit, consts);
  gemm_abT<<<dim3(48, 16), dim3(256), 0, stream>>>(x, W_qkvg, qkvg, 1024, 3072, 768);
  pack_kernel<<<dim3(16, 12), dim3(256), 0, stream>>>(qkvg, g_norm_w, qhT, khT, ghT, g2);
  flash_kernel<<<dim3(32, 12), dim3(256), 0, stream>>>(qhT, khT, ghT, g2, qkvg, consts, y);
  gemm_abT<<<dim3(12, 16), dim3(256), 0, stream>>>(y, W_out, out, 1024, 768, 768);
}

// Round 3
// 335.873 us; speedup vs baseline: 14.7848x; 1.2364x over previous
//
#include <hip/hip_runtime.h>
#include <math.h>

#define TSEQ 1024
#define CD   768
#define HN   12
#define DD   64

// workspace float offsets
#define OFF_QKVG   0          // 1024*3072
#define OFF_QHT    3145728    // 12*64*1024
#define OFF_KHT    3932160
#define OFF_GHT    4718592
#define OFF_G2     5505024    // 12*1024
#define OFF_Y      5517312    // 1024*768
#define OFF_CONSTS 6303744    // 241 floats, pad to 256
#define OFF_OPART  6304000    // 12*1024*64 = 786432
#define OFF_LS     7090432    // 12*1024
#define OFF_PD     7102720    // 12*1024  (end 7115008 floats = 28.5 MB)
#define NZERO4     202752     // (786432+12288+12288)/4

// consts per head (stride 20): [0]=lam*dp_scale/6.4, [1]=(1-lam)*logk_scale,
// [2]=clip(beta)/2, [3]=out_scale, [4..11]=1/(4*tau), [12..19]=log2(w+1e-12)
// alpha at [240]

__global__ __launch_bounds__(64) void prep_kernel(
    const float* __restrict__ lam_p, const float* __restrict__ log_tau,
    const float* __restrict__ logit_w, const float* __restrict__ beta,
    const float* __restrict__ out_scale, const float* __restrict__ dp_scale,
    const float* __restrict__ logk_scale, const float* __restrict__ dt_logit,
    float* __restrict__ consts) {
  int h = threadIdx.x;
  if (h == 0) {
    float dt = 1.0f / (1.0f + __expf(-dt_logit[0]));
    consts[12 * 20] = 0.1f * dt;  // ESR_ALPHA * dt
  }
  if (h < HN) {
    float lam = lam_p[0];
    float* c = consts + h * 20;
    c[0] = lam * dp_scale[h] * (1.0f / 6.4f);  // sqrt(64)*0.8 = 6.4
    c[1] = (1.0f - lam) * logk_scale[h];
    float b = fminf(fmaxf(beta[h], 0.5f), 2.5f);
    c[2] = 0.5f * b;
    c[3] = out_scale[h];
    float m = -1e30f;
    float lw[8];
    for (int t = 0; t < 8; t++) { lw[t] = logit_w[h * 8 + t]; m = fmaxf(m, lw[t]); }
    float s = 0.f;
    float e[8];
    for (int t = 0; t < 8; t++) { e[t] = __expf(lw[t] - m); s += e[t]; }
    for (int t = 0; t < 8; t++) {
      float w = e[t] / s;
      c[12 + t] = log2f(w + 1e-12f);     // log2 domain
      float tau = fmaxf(__expf(log_tau[h * 8 + t]), 1e-6f);
      c[4 + t] = 1.0f / (4.0f * tau);
    }
  }
}

__global__ __launch_bounds__(256) void zero_kernel(float4* __restrict__ p, int n4) {
  int i = blockIdx.x * 256 + threadIdx.x;
  for (; i < n4; i += gridDim.x * 256) p[i] = make_float4(0.f, 0.f, 0.f, 0.f);
}

// C[M][N] = A[M][K] @ B[N][K]^T, all row-major, fp32. 64x64 tiles, kstep 32.
__global__ __launch_bounds__(256) void gemm_abT(
    const float* __restrict__ A, const float* __restrict__ B,
    float* __restrict__ Cm, int M, int N, int K) {
  __shared__ __align__(16) float AsT[32][68];
  __shared__ __align__(16) float BsT[32][68];
  int t = threadIdx.x;
  int tx = t & 15, ty = t >> 4;
  int n0 = blockIdx.x * 64, m0 = blockIdx.y * 64;
  float acc[4][4] = {};
  for (int k0 = 0; k0 < K; k0 += 32) {
    __syncthreads();
#pragma unroll 4
    for (int rep = 0; rep < 8; rep++) {
      int idx = rep * 256 + t;
      int r = idx >> 5, kk = idx & 31;
      AsT[kk][r] = A[(m0 + r) * K + k0 + kk];
      BsT[kk][r] = B[(n0 + r) * K + k0 + kk];
    }
    __syncthreads();
#pragma unroll 8
    for (int kk = 0; kk < 32; kk++) {
      float4 a4 = *(const float4*)&AsT[kk][4 * ty];
      float4 b4 = *(const float4*)&BsT[kk][4 * tx];
      acc[0][0] += a4.x * b4.x; acc[0][1] += a4.x * b4.y; acc[0][2] += a4.x * b4.z; acc[0][3] += a4.x * b4.w;
      acc[1][0] += a4.y * b4.x; acc[1][1] += a4.y * b4.y; acc[1][2] += a4.y * b4.z; acc[1][3] += a4.y * b4.w;
      acc[2][0] += a4.z * b4.x; acc[2][1] += a4.z * b4.y; acc[2][2] += a4.z * b4.z; acc[2][3] += a4.z * b4.w;
      acc[3][0] += a4.w * b4.x; acc[3][1] += a4.w * b4.y; acc[3][2] += a4.w * b4.z; acc[3][3] += a4.w * b4.w;
    }
  }
#pragma unroll
  for (int i = 0; i < 4; i++) {
    float4 o = make_float4(acc[i][0], acc[i][1], acc[i][2], acc[i][3]);
    *(float4*)&Cm[(m0 + 4 * ty + i) * N + n0 + 4 * tx] = o;
  }
}

// Extract q,k,g heads from qkvg, rmsnorm g, write d-major transposed [H][D][T];
// also g2[h][t] = ||g_norm||^2.
__global__ __launch_bounds__(256) void pack_kernel(
    const float* __restrict__ qkvg, const float* __restrict__ g_norm_w,
    float* __restrict__ qhT, float* __restrict__ khT,
    float* __restrict__ ghT, float* __restrict__ g2) {
  int h = blockIdx.y;
  int t0 = blockIdx.x * 64;
  int t = threadIdx.x;
  __shared__ float tile[64][65];
  __shared__ float gw[64];
  __shared__ float part1[64][4], part2[64][4];
  __shared__ float rr[64];
  if (t < 64) gw[t] = g_norm_w[t];
  const int offs[3] = {0, CD, 3 * CD};        // q, k, g column offsets in qkvg
  float* const outs[3] = {qhT, khT, ghT};
  for (int a = 0; a < 3; a++) {
    __syncthreads();
#pragma unroll 4
    for (int rep = 0; rep < 16; rep++) {
      int idx = rep * 256 + t;
      int r = idx >> 6, d = idx & 63;
      tile[r][d] = qkvg[(t0 + r) * 3072 + offs[a] + h * 64 + d];
    }
    __syncthreads();
    if (a == 2) {
      int row = t & 63, seg = t >> 6;
      float s1 = 0.f, s2 = 0.f;
      for (int d = seg * 16; d < seg * 16 + 16; d++) {
        float g = tile[row][d], w = gw[d];
        s1 += g * g;
        s2 += g * g * w * w;
      }
      part1[row][seg] = s1; part2[row][seg] = s2;
      __syncthreads();
      if (t < 64) {
        float a1 = part1[t][0] + part1[t][1] + part1[t][2] + part1[t][3];
        float a2 = part2[t][0] + part2[t][1] + part2[t][2] + part2[t][3];
        float rms = rsqrtf(a1 * (1.0f / 64.0f) + 1e-6f);
        rr[t] = rms;
        g2[h * TSEQ + t0 + t] = rms * rms * a2;
      }
      __syncthreads();
    }
    float* outp = outs[a];
#pragma unroll 4
    for (int rep = 0; rep < 16; rep++) {
      int idx = rep * 256 + t;
      int d = idx >> 6, tc = idx & 63;
      float v = tile[tc][d];
      if (a == 2) v *= rr[tc] * gw[d];
      outp[(h * 64 + d) * TSEQ + t0 + tc] = v;
    }
  }
}

// Split-j flash: block = (head h, i-tile of 32 rows, chunk of <=2 j-tiles).
// Accumulates partial O (unnormalized) and row-sum ls into global via atomics.
// Diagonal P_ii has a single owner chunk (the last one) -> plain store.
__global__ __launch_bounds__(256, 2) void flash_kernel(
    const float* __restrict__ qhT, const float* __restrict__ khT,
    const float* __restrict__ ghT, const float* __restrict__ g2,
    const float* __restrict__ qkvg, const float* __restrict__ consts,
    float* __restrict__ Opart, float* __restrict__ lsp, float* __restrict__ pdp) {
  int h = blockIdx.y;
  // decode work unit: 144 chunks per head, heavy (large it) first
  int uu = 143 - (int)blockIdx.x;
  int it = 0, rem = uu;
  for (it = 0; it < 32; ++it) {
    int njt_ = (it >> 1) + 1;
    int nc = (njt_ + 1) >> 1;
    if (rem < nc) break;
    rem -= nc;
  }
  int njt = (it >> 1) + 1;
  int jt0 = rem * 2;
  int jt1 = (jt0 + 2 < njt) ? (jt0 + 2) : njt;
  bool owns_diag = (jt1 == njt);
  int i0 = it * 32;
  int t = threadIdx.x;
  int tx = t & 15, ty = t >> 4;

  __shared__ __align__(16) float qsT[64][34];    // [kk][r]
  __shared__ __align__(16) float gisT[64][34];
  __shared__ __align__(16) float kvT[64 * 68];   // K^T in score phase, V in O phase
  __shared__ __align__(16) float gjsT[64][68];
  __shared__ float ps[32][65];
  __shared__ float g2i[32], g2j[64], ls[32], pdiag[32];

  const float* ch = consts + h * 20;
  float dpc = ch[0] * 1.44269504089f;  // exp2-domain dot-product coeff
  float lkc = ch[1];
  float bh2 = ch[2];
  float inv4tau[8], logw[8];
#pragma unroll
  for (int tt = 0; tt < 8; tt++) { inv4tau[tt] = ch[4 + tt]; logw[tt] = ch[12 + tt]; }

#pragma unroll 4
  for (int rep = 0; rep < 8; rep++) {
    int idx = rep * 256 + t;
    int kk = idx >> 5, r = idx & 31;
    qsT[kk][r] = qhT[(h * 64 + kk) * TSEQ + i0 + r];
    gisT[kk][r] = ghT[(h * 64 + kk) * TSEQ + i0 + r];
  }
  if (t < 32) { g2i[t] = g2[h * TSEQ + i0 + t]; ls[t] = 0.f; pdiag[t] = 0.f; }

  float O[2][4] = {};

  for (int jt = jt0; jt < jt1; jt++) {
    int j0 = jt * 64;
    __syncthreads();
#pragma unroll 4
    for (int rep = 0; rep < 16; rep++) {
      int idx = rep * 256 + t;
      int kk = idx >> 6, c = idx & 63;
      kvT[kk * 68 + c] = khT[(h * 64 + kk) * TSEQ + j0 + c];
      gjsT[kk][c] = ghT[(h * 64 + kk) * TSEQ + j0 + c];
    }
    if (t < 64) g2j[t] = g2[h * TSEQ + j0 + t];
    __syncthreads();

    // score dots: rows r = 2ty+{0,1}, cols c = 4tx+{0..3}
    float aqk[2][4] = {}, agg[2][4] = {};
#pragma unroll 8
    for (int kk = 0; kk < 64; kk++) {
      float2 aq = *(const float2*)&qsT[kk][2 * ty];
      float2 ag = *(const float2*)&gisT[kk][2 * ty];
      float4 bk = *(const float4*)&kvT[kk * 68 + 4 * tx];
      float4 bg = *(const float4*)&gjsT[kk][4 * tx];
      aqk[0][0] += aq.x * bk.x; aqk[0][1] += aq.x * bk.y; aqk[0][2] += aq.x * bk.z; aqk[0][3] += aq.x * bk.w;
      aqk[1][0] += aq.y * bk.x; aqk[1][1] += aq.y * bk.y; aqk[1][2] += aq.y * bk.z; aqk[1][3] += aq.y * bk.w;
      agg[0][0] += ag.x * bg.x; agg[0][1] += ag.x * bg.y; agg[0][2] += ag.x * bg.z; agg[0][3] += ag.x * bg.w;
      agg[1][0] += ag.y * bg.x; agg[1][1] += ag.y * bg.y; agg[1][2] += ag.y * bg.z; agg[1][3] += ag.y * bg.w;
    }

    // blended -> p = exp2(b2); range analysis: |b2| < ~10 so no max-shift needed
    float rs[2] = {0.f, 0.f};
#pragma unroll
    for (int i2 = 0; i2 < 2; i2++) {
      int r = 2 * ty + i2;
      int gi = i0 + r;
      float g2iv = g2i[r];
#pragma unroll
      for (int j4 = 0; j4 < 4; j4++) {
        int c = 4 * tx + j4;
        int gj = j0 + c;
        float s = fmaxf(g2iv + g2j[c] - 2.0f * agg[i2][j4], 0.0f);
        float se = 0.f;
#pragma unroll
        for (int tt = 0; tt < 8; tt++) {
          float lv = __builtin_amdgcn_logf(fmaf(s, inv4tau[tt], 1.0f));  // log2
          se += __builtin_amdgcn_exp2f(fmaf(-bh2, lv, logw[tt]));
        }
        float lse = __builtin_amdgcn_logf(se + 1e-30f);  // log2(se)
        float b = fmaf(dpc, aqk[i2][j4], lkc * lse);
        float p = (gj <= gi) ? __builtin_amdgcn_exp2f(b) : 0.0f;
        ps[r][c] = p;
        rs[i2] += p;
        if (gj == gi) pdiag[r] = p;
      }
    }
    // in-register row-sum across the 16-lane tx group
#pragma unroll
    for (int m = 1; m < 16; m <<= 1) {
      rs[0] += __shfl_xor(rs[0], m, 64);
      rs[1] += __shfl_xor(rs[1], m, 64);
    }
    if (tx == 0) { ls[2 * ty] += rs[0]; ls[2 * ty + 1] += rs[1]; }
    __syncthreads();

    // stage V into kvT (K no longer needed)
#pragma unroll 4
    for (int rep = 0; rep < 16; rep++) {
      int idx = rep * 256 + t;
      int jj = idx >> 6, d = idx & 63;
      kvT[jj * 68 + d] = qkvg[(j0 + jj) * 3072 + 2 * CD + h * 64 + d];
    }
    __syncthreads();

    // O += P_tile @ V_tile
#pragma unroll 8
    for (int jj = 0; jj < 64; jj++) {
      float p0 = ps[2 * ty][jj];
      float p1 = ps[2 * ty + 1][jj];
      float4 v4 = *(const float4*)&kvT[jj * 68 + 4 * tx];
      O[0][0] += p0 * v4.x; O[0][1] += p0 * v4.y; O[0][2] += p0 * v4.z; O[0][3] += p0 * v4.w;
      O[1][0] += p1 * v4.x; O[1][1] += p1 * v4.y; O[1][2] += p1 * v4.z; O[1][3] += p1 * v4.w;
    }
  }
  __syncthreads();

  // accumulate partials to global
  float* Ob = Opart + (size_t)(h * 1024 + i0) * 64;
#pragma unroll
  for (int i2 = 0; i2 < 2; i2++) {
    int r = 2 * ty + i2;
#pragma unroll
    for (int k = 0; k < 4; k++)
      atomicAdd(&Ob[r * 64 + 4 * tx + k], O[i2][k]);
  }
  if (t < 32) atomicAdd(&lsp[h * TSEQ + i0 + t], ls[t]);
  if (owns_diag && t < 32) pdp[h * TSEQ + i0 + t] = pdiag[t];
}

// y_i = osc*(c1*(P@v)_i + c2*v_i) with c1,c2 from P_ii (analytic P_rev)
__global__ __launch_bounds__(256) void finalize_kernel(
    const float* __restrict__ Opart, const float* __restrict__ lsp,
    const float* __restrict__ pdp, const float* __restrict__ qkvg,
    const float* __restrict__ consts, float* __restrict__ y) {
  int h = blockIdx.y;
  int t = threadIdx.x;
  int rl = t >> 4, d4 = t & 15;
  int gi = blockIdx.x * 16 + rl;
  float alpha = consts[240];
  float osc = consts[h * 20 + 3];
  float l = fmaxf(lsp[h * TSEQ + gi], 1e-12f);
  float Pii = pdp[h * TSEQ + gi] / l;
  float inv1p = 1.0f / (1.0f + Pii);
  float c1 = (1.0f - alpha) + alpha * inv1p;
  float c2 = alpha * Pii * inv1p;
  float invl = 1.0f / l;
  float4 Ov = *(const float4*)&Opart[(size_t)(h * 1024 + gi) * 64 + 4 * d4];
  float4 vi = *(const float4*)&qkvg[gi * 3072 + 2 * CD + h * 64 + 4 * d4];
  float4 o;
  o.x = osc * (c1 * Ov.x * invl + c2 * vi.x);
  o.y = osc * (c1 * Ov.y * invl + c2 * vi.y);
  o.z = osc * (c1 * Ov.z * invl + c2 * vi.z);
  o.w = osc * (c1 * Ov.w * invl + c2 * vi.w);
  *(float4*)&y[gi * CD + h * 64 + 4 * d4] = o;
}

extern "C" void kernel_launch(void* const* d_in, const int* in_sizes, int n_in,
                              void* d_out, int out_size, void* d_ws, size_t ws_size,
                              hipStream_t stream) {
  (void)in_sizes; (void)n_in; (void)out_size; (void)ws_size;
  const float* x          = (const float*)d_in[0];
  const float* W_qkvg     = (const float*)d_in[1];
  const float* W_out      = (const float*)d_in[2];
  const float* lam        = (const float*)d_in[3];
  const float* log_tau    = (const float*)d_in[4];
  const float* logit_w    = (const float*)d_in[5];
  const float* beta       = (const float*)d_in[6];
  const float* out_scale  = (const float*)d_in[7];
  const float* dp_scale   = (const float*)d_in[8];
  const float* logk_scale = (const float*)d_in[9];
  const float* dt_logit   = (const float*)d_in[10];
  const float* g_norm_w   = (const float*)d_in[11];
  float* ws = (float*)d_ws;
  float* qkvg   = ws + OFF_QKVG;
  float* qhT    = ws + OFF_QHT;
  float* khT    = ws + OFF_KHT;
  float* ghT    = ws + OFF_GHT;
  float* g2     = ws + OFF_G2;
  float* y      = ws + OFF_Y;
  float* consts = ws + OFF_CONSTS;
  float* Opart  = ws + OFF_OPART;
  float* lsp    = ws + OFF_LS;
  float* pdp    = ws + OFF_PD;
  float* out = (float*)d_out;

  prep_kernel<<<dim3(1), dim3(64), 0, stream>>>(lam, log_tau, logit_w, beta,
                                                out_scale, dp_scale, logk_scale,
                                                dt_logit, consts);
  zero_kernel<<<dim3(512), dim3(256), 0, stream>>>((float4*)Opart, NZERO4);
  gemm_abT<<<dim3(48, 16), dim3(256), 0, stream>>>(x, W_qkvg, qkvg, 1024, 3072, 768);
  pack_kernel<<<dim3(16, 12), dim3(256), 0, stream>>>(qkvg, g_norm_w, qhT, khT, ghT, g2);
  flash_kernel<<<dim3(144, 12), dim3(256), 0, stream>>>(qhT, khT, ghT, g2, qkvg, consts,
                                                        Opart, lsp, pdp);
  finalize_kernel<<<dim3(64, 12), dim3(256), 0, stream>>>(Opart, lsp, pdp, qkvg, consts, y);
  gemm_abT<<<dim3(12, 16), dim3(256), 0, stream>>>(y, W_out, out, 1024, 768, 768);
}

// Round 4
// 265.026 us; speedup vs baseline: 18.7370x; 1.2673x over previous
//
#include <hip/hip_runtime.h>
#include <math.h>

#define TSEQ 1024
#define CD   768
#define HN   12
#define DD   64

// workspace float offsets
#define OFF_QKVG   0          // 1024*3072
#define OFF_QHT    3145728    // 12*64*1024
#define OFF_KHT    3932160
#define OFF_GHT    4718592
#define OFF_G2     5505024    // 12*1024
#define OFF_Y      5517312    // 1024*768
#define OFF_CONSTS 6303744    // 241 floats, pad to 256
#define OFF_OPART  6304000    // 12*1024*64 = 786432
#define OFF_LS     7090432    // 12*1024
#define OFF_PD     7102720    // 12*1024  (end 7115008 floats = 28.5 MB)
#define NZERO4     202752     // (786432+12288+12288)/4

typedef __bf16 bf16x8 __attribute__((ext_vector_type(8)));
typedef float  f32x4  __attribute__((ext_vector_type(4)));

__device__ inline unsigned short f2bf(float f) {
  unsigned int u = __float_as_uint(f);
  return (unsigned short)((u + 0x7fffu + ((u >> 16) & 1u)) >> 16);  // RNE
}

// consts per head (stride 20): [0]=lam*dp_scale/6.4, [1]=(1-lam)*logk_scale,
// [2]=clip(beta)/2, [3]=out_scale, [4..11]=1/(4*tau), [12..19]=log2(w+1e-12)
// alpha at [240]

__global__ __launch_bounds__(64) void prep_kernel(
    const float* __restrict__ lam_p, const float* __restrict__ log_tau,
    const float* __restrict__ logit_w, const float* __restrict__ beta,
    const float* __restrict__ out_scale, const float* __restrict__ dp_scale,
    const float* __restrict__ logk_scale, const float* __restrict__ dt_logit,
    float* __restrict__ consts) {
  int h = threadIdx.x;
  if (h == 0) {
    float dt = 1.0f / (1.0f + __expf(-dt_logit[0]));
    consts[12 * 20] = 0.1f * dt;  // ESR_ALPHA * dt
  }
  if (h < HN) {
    float lam = lam_p[0];
    float* c = consts + h * 20;
    c[0] = lam * dp_scale[h] * (1.0f / 6.4f);  // sqrt(64)*0.8 = 6.4
    c[1] = (1.0f - lam) * logk_scale[h];
    float b = fminf(fmaxf(beta[h], 0.5f), 2.5f);
    c[2] = 0.5f * b;
    c[3] = out_scale[h];
    float m = -1e30f;
    float lw[8];
    for (int t = 0; t < 8; t++) { lw[t] = logit_w[h * 8 + t]; m = fmaxf(m, lw[t]); }
    float s = 0.f;
    float e[8];
    for (int t = 0; t < 8; t++) { e[t] = __expf(lw[t] - m); s += e[t]; }
    for (int t = 0; t < 8; t++) {
      float w = e[t] / s;
      c[12 + t] = log2f(w + 1e-12f);     // log2 domain
      float tau = fmaxf(__expf(log_tau[h * 8 + t]), 1e-6f);
      c[4 + t] = 1.0f / (4.0f * tau);
    }
  }
}

__global__ __launch_bounds__(256) void zero_kernel(float4* __restrict__ p, int n4) {
  int i = blockIdx.x * 256 + threadIdx.x;
  for (; i < n4; i += gridDim.x * 256) p[i] = make_float4(0.f, 0.f, 0.f, 0.f);
}

// C[M][N] = A[M][K] @ B[N][K]^T, fp32 in/out, bf16 MFMA inside.
// Block = 128 threads (2 waves); block tile 64(M)x64(N); K-step 32.
// Wave w computes rows 32w..32w+31 (2x4 grid of 16x16 MFMA tiles).
__global__ __launch_bounds__(128) void gemm_abT_bf16(
    const float* __restrict__ A, const float* __restrict__ B,
    float* __restrict__ Cm, int M, int N, int K) {
  // row stride 40 bf16 (80B = 20 banks -> worst 2-way conflict, free)
  __shared__ __align__(16) unsigned short As[64 * 40];
  __shared__ __align__(16) unsigned short Bs[64 * 40];
  int t = threadIdx.x;
  int lane = t & 63, w = t >> 6;
  int quad = lane >> 4, col = lane & 15;
  int n0 = blockIdx.x * 64, m0 = blockIdx.y * 64;

  f32x4 acc[2][4] = {};

  for (int k0 = 0; k0 < K; k0 += 32) {
    __syncthreads();
    // stage A,B 64x32 fp32 -> bf16 LDS (8 float2-pairs per thread per matrix)
#pragma unroll 4
    for (int rep = 0; rep < 8; rep++) {
      int pidx = rep * 128 + t;          // 0..1023
      int r = pidx >> 4, kp = pidx & 15; // row, k-pair
      float2 a2 = *(const float2*)&A[(size_t)(m0 + r) * K + k0 + 2 * kp];
      float2 b2 = *(const float2*)&B[(size_t)(n0 + r) * K + k0 + 2 * kp];
      *(unsigned int*)&As[r * 40 + 2 * kp] =
          (unsigned int)f2bf(a2.x) | ((unsigned int)f2bf(a2.y) << 16);
      *(unsigned int*)&Bs[r * 40 + 2 * kp] =
          (unsigned int)f2bf(b2.x) | ((unsigned int)f2bf(b2.y) << 16);
    }
    __syncthreads();

    bf16x8 af[2], bf[4];
#pragma unroll
    for (int mi = 0; mi < 2; mi++)
      af[mi] = *(const bf16x8*)&As[(32 * w + mi * 16 + col) * 40 + quad * 8];
#pragma unroll
    for (int ni = 0; ni < 4; ni++)
      bf[ni] = *(const bf16x8*)&Bs[(ni * 16 + col) * 40 + quad * 8];
#pragma unroll
    for (int mi = 0; mi < 2; mi++)
#pragma unroll
      for (int ni = 0; ni < 4; ni++)
        acc[mi][ni] = __builtin_amdgcn_mfma_f32_16x16x32_bf16(
            af[mi], bf[ni], acc[mi][ni], 0, 0, 0);
  }

  // epilogue: C/D layout col=lane&15, row=quad*4+reg
#pragma unroll
  for (int mi = 0; mi < 2; mi++) {
#pragma unroll
    for (int ni = 0; ni < 4; ni++) {
#pragma unroll
      for (int reg = 0; reg < 4; reg++) {
        int row = m0 + 32 * w + mi * 16 + quad * 4 + reg;
        Cm[(size_t)row * N + n0 + ni * 16 + col] = acc[mi][ni][reg];
      }
    }
  }
}

// Extract q,k,g heads from qkvg, rmsnorm g, write d-major transposed [H][D][T];
// also g2[h][t] = ||g_norm||^2.
__global__ __launch_bounds__(256) void pack_kernel(
    const float* __restrict__ qkvg, const float* __restrict__ g_norm_w,
    float* __restrict__ qhT, float* __restrict__ khT,
    float* __restrict__ ghT, float* __restrict__ g2) {
  int h = blockIdx.y;
  int t0 = blockIdx.x * 64;
  int t = threadIdx.x;
  __shared__ float tile[64][65];
  __shared__ float gw[64];
  __shared__ float part1[64][4], part2[64][4];
  __shared__ float rr[64];
  if (t < 64) gw[t] = g_norm_w[t];
  const int offs[3] = {0, CD, 3 * CD};        // q, k, g column offsets in qkvg
  float* const outs[3] = {qhT, khT, ghT};
  for (int a = 0; a < 3; a++) {
    __syncthreads();
#pragma unroll 4
    for (int rep = 0; rep < 16; rep++) {
      int idx = rep * 256 + t;
      int r = idx >> 6, d = idx & 63;
      tile[r][d] = qkvg[(t0 + r) * 3072 + offs[a] + h * 64 + d];
    }
    __syncthreads();
    if (a == 2) {
      int row = t & 63, seg = t >> 6;
      float s1 = 0.f, s2 = 0.f;
      for (int d = seg * 16; d < seg * 16 + 16; d++) {
        float g = tile[row][d], w = gw[d];
        s1 += g * g;
        s2 += g * g * w * w;
      }
      part1[row][seg] = s1; part2[row][seg] = s2;
      __syncthreads();
      if (t < 64) {
        float a1 = part1[t][0] + part1[t][1] + part1[t][2] + part1[t][3];
        float a2 = part2[t][0] + part2[t][1] + part2[t][2] + part2[t][3];
        float rms = rsqrtf(a1 * (1.0f / 64.0f) + 1e-6f);
        rr[t] = rms;
        g2[h * TSEQ + t0 + t] = rms * rms * a2;
      }
      __syncthreads();
    }
    float* outp = outs[a];
#pragma unroll 4
    for (int rep = 0; rep < 16; rep++) {
      int idx = rep * 256 + t;
      int d = idx >> 6, tc = idx & 63;
      float v = tile[tc][d];
      if (a == 2) v *= rr[tc] * gw[d];
      outp[(h * 64 + d) * TSEQ + t0 + tc] = v;
    }
  }
}

// Split-j flash: block = (head h, i-tile of 32 rows, chunk of <=2 j-tiles).
// Accumulates partial O (unnormalized) and row-sum ls into global via atomics.
// Diagonal P_ii has a single owner chunk (the last one) -> plain store.
__global__ __launch_bounds__(256, 2) void flash_kernel(
    const float* __restrict__ qhT, const float* __restrict__ khT,
    const float* __restrict__ ghT, const float* __restrict__ g2,
    const float* __restrict__ qkvg, const float* __restrict__ consts,
    float* __restrict__ Opart, float* __restrict__ lsp, float* __restrict__ pdp) {
  int h = blockIdx.y;
  // decode work unit: 144 chunks per head, heavy (large it) first
  int uu = 143 - (int)blockIdx.x;
  int it = 0, rem = uu;
  for (it = 0; it < 32; ++it) {
    int njt_ = (it >> 1) + 1;
    int nc = (njt_ + 1) >> 1;
    if (rem < nc) break;
    rem -= nc;
  }
  int njt = (it >> 1) + 1;
  int jt0 = rem * 2;
  int jt1 = (jt0 + 2 < njt) ? (jt0 + 2) : njt;
  bool owns_diag = (jt1 == njt);
  int i0 = it * 32;
  int t = threadIdx.x;
  int tx = t & 15, ty = t >> 4;

  __shared__ __align__(16) float qsT[64][34];    // [kk][r]
  __shared__ __align__(16) float gisT[64][34];
  __shared__ __align__(16) float kvT[64 * 68];   // K^T in score phase, V in O phase
  __shared__ __align__(16) float gjsT[64][68];
  __shared__ float ps[32][65];
  __shared__ float g2i[32], g2j[64], ls[32], pdiag[32];

  const float* ch = consts + h * 20;
  float dpc = ch[0] * 1.44269504089f;  // exp2-domain dot-product coeff
  float lkc = ch[1];
  float bh2 = ch[2];
  float inv4tau[8], logw[8];
#pragma unroll
  for (int tt = 0; tt < 8; tt++) { inv4tau[tt] = ch[4 + tt]; logw[tt] = ch[12 + tt]; }

#pragma unroll 4
  for (int rep = 0; rep < 8; rep++) {
    int idx = rep * 256 + t;
    int kk = idx >> 5, r = idx & 31;
    qsT[kk][r] = qhT[(h * 64 + kk) * TSEQ + i0 + r];
    gisT[kk][r] = ghT[(h * 64 + kk) * TSEQ + i0 + r];
  }
  if (t < 32) { g2i[t] = g2[h * TSEQ + i0 + t]; ls[t] = 0.f; pdiag[t] = 0.f; }

  float O[2][4] = {};

  for (int jt = jt0; jt < jt1; jt++) {
    int j0 = jt * 64;
    __syncthreads();
#pragma unroll 4
    for (int rep = 0; rep < 16; rep++) {
      int idx = rep * 256 + t;
      int kk = idx >> 6, c = idx & 63;
      kvT[kk * 68 + c] = khT[(h * 64 + kk) * TSEQ + j0 + c];
      gjsT[kk][c] = ghT[(h * 64 + kk) * TSEQ + j0 + c];
    }
    if (t < 64) g2j[t] = g2[h * TSEQ + j0 + t];
    __syncthreads();

    // score dots: rows r = 2ty+{0,1}, cols c = 4tx+{0..3}
    float aqk[2][4] = {}, agg[2][4] = {};
#pragma unroll 8
    for (int kk = 0; kk < 64; kk++) {
      float2 aq = *(const float2*)&qsT[kk][2 * ty];
      float2 ag = *(const float2*)&gisT[kk][2 * ty];
      float4 bk = *(const float4*)&kvT[kk * 68 + 4 * tx];
      float4 bg = *(const float4*)&gjsT[kk][4 * tx];
      aqk[0][0] += aq.x * bk.x; aqk[0][1] += aq.x * bk.y; aqk[0][2] += aq.x * bk.z; aqk[0][3] += aq.x * bk.w;
      aqk[1][0] += aq.y * bk.x; aqk[1][1] += aq.y * bk.y; aqk[1][2] += aq.y * bk.z; aqk[1][3] += aq.y * bk.w;
      agg[0][0] += ag.x * bg.x; agg[0][1] += ag.x * bg.y; agg[0][2] += ag.x * bg.z; agg[0][3] += ag.x * bg.w;
      agg[1][0] += ag.y * bg.x; agg[1][1] += ag.y * bg.y; agg[1][2] += ag.y * bg.z; agg[1][3] += ag.y * bg.w;
    }

    // blended -> p = exp2(b2); range analysis: |b2| < ~10 so no max-shift needed
    float rs[2] = {0.f, 0.f};
#pragma unroll
    for (int i2 = 0; i2 < 2; i2++) {
      int r = 2 * ty + i2;
      int gi = i0 + r;
      float g2iv = g2i[r];
#pragma unroll
      for (int j4 = 0; j4 < 4; j4++) {
        int c = 4 * tx + j4;
        int gj = j0 + c;
        float s = fmaxf(g2iv + g2j[c] - 2.0f * agg[i2][j4], 0.0f);
        float se = 0.f;
#pragma unroll
        for (int tt = 0; tt < 8; tt++) {
          float lv = __builtin_amdgcn_logf(fmaf(s, inv4tau[tt], 1.0f));  // log2
          se += __builtin_amdgcn_exp2f(fmaf(-bh2, lv, logw[tt]));
        }
        float lse = __builtin_amdgcn_logf(se + 1e-30f);  // log2(se)
        float b = fmaf(dpc, aqk[i2][j4], lkc * lse);
        float p = (gj <= gi) ? __builtin_amdgcn_exp2f(b) : 0.0f;
        ps[r][c] = p;
        rs[i2] += p;
        if (gj == gi) pdiag[r] = p;
      }
    }
    // in-register row-sum across the 16-lane tx group
#pragma unroll
    for (int m = 1; m < 16; m <<= 1) {
      rs[0] += __shfl_xor(rs[0], m, 64);
      rs[1] += __shfl_xor(rs[1], m, 64);
    }
    if (tx == 0) { ls[2 * ty] += rs[0]; ls[2 * ty + 1] += rs[1]; }
    __syncthreads();

    // stage V into kvT (K no longer needed)
#pragma unroll 4
    for (int rep = 0; rep < 16; rep++) {
      int idx = rep * 256 + t;
      int jj = idx >> 6, d = idx & 63;
      kvT[jj * 68 + d] = qkvg[(j0 + jj) * 3072 + 2 * CD + h * 64 + d];
    }
    __syncthreads();

    // O += P_tile @ V_tile
#pragma unroll 8
    for (int jj = 0; jj < 64; jj++) {
      float p0 = ps[2 * ty][jj];
      float p1 = ps[2 * ty + 1][jj];
      float4 v4 = *(const float4*)&kvT[jj * 68 + 4 * tx];
      O[0][0] += p0 * v4.x; O[0][1] += p0 * v4.y; O[0][2] += p0 * v4.z; O[0][3] += p0 * v4.w;
      O[1][0] += p1 * v4.x; O[1][1] += p1 * v4.y; O[1][2] += p1 * v4.z; O[1][3] += p1 * v4.w;
    }
  }
  __syncthreads();

  // accumulate partials to global
  float* Ob = Opart + (size_t)(h * 1024 + i0) * 64;
#pragma unroll
  for (int i2 = 0; i2 < 2; i2++) {
    int r = 2 * ty + i2;
#pragma unroll
    for (int k = 0; k < 4; k++)
      atomicAdd(&Ob[r * 64 + 4 * tx + k], O[i2][k]);
  }
  if (t < 32) atomicAdd(&lsp[h * TSEQ + i0 + t], ls[t]);
  if (owns_diag && t < 32) pdp[h * TSEQ + i0 + t] = pdiag[t];
}

// y_i = osc*(c1*(P@v)_i + c2*v_i) with c1,c2 from P_ii (analytic P_rev)
__global__ __launch_bounds__(256) void finalize_kernel(
    const float* __restrict__ Opart, const float* __restrict__ lsp,
    const float* __restrict__ pdp, const float* __restrict__ qkvg,
    const float* __restrict__ consts, float* __restrict__ y) {
  int h = blockIdx.y;
  int t = threadIdx.x;
  int rl = t >> 4, d4 = t & 15;
  int gi = blockIdx.x * 16 + rl;
  float alpha = consts[240];
  float osc = consts[h * 20 + 3];
  float l = fmaxf(lsp[h * TSEQ + gi], 1e-12f);
  float Pii = pdp[h * TSEQ + gi] / l;
  float inv1p = 1.0f / (1.0f + Pii);
  float c1 = (1.0f - alpha) + alpha * inv1p;
  float c2 = alpha * Pii * inv1p;
  float invl = 1.0f / l;
  float4 Ov = *(const float4*)&Opart[(size_t)(h * 1024 + gi) * 64 + 4 * d4];
  float4 vi = *(const float4*)&qkvg[gi * 3072 + 2 * CD + h * 64 + 4 * d4];
  float4 o;
  o.x = osc * (c1 * Ov.x * invl + c2 * vi.x);
  o.y = osc * (c1 * Ov.y * invl + c2 * vi.y);
  o.z = osc * (c1 * Ov.z * invl + c2 * vi.z);
  o.w = osc * (c1 * Ov.w * invl + c2 * vi.w);
  *(float4*)&y[gi * CD + h * 64 + 4 * d4] = o;
}

extern "C" void kernel_launch(void* const* d_in, const int* in_sizes, int n_in,
                              void* d_out, int out_size, void* d_ws, size_t ws_size,
                              hipStream_t stream) {
  (void)in_sizes; (void)n_in; (void)out_size; (void)ws_size;
  const float* x          = (const float*)d_in[0];
  const float* W_qkvg     = (const float*)d_in[1];
  const float* W_out      = (const float*)d_in[2];
  const float* lam        = (const float*)d_in[3];
  const float* log_tau    = (const float*)d_in[4];
  const float* logit_w    = (const float*)d_in[5];
  const float* beta       = (const float*)d_in[6];
  const float* out_scale  = (const float*)d_in[7];
  const float* dp_scale   = (const float*)d_in[8];
  const float* logk_scale = (const float*)d_in[9];
  const float* dt_logit   = (const float*)d_in[10];
  const float* g_norm_w   = (const float*)d_in[11];
  float* ws = (float*)d_ws;
  float* qkvg   = ws + OFF_QKVG;
  float* qhT    = ws + OFF_QHT;
  float* khT    = ws + OFF_KHT;
  float* ghT    = ws + OFF_GHT;
  float* g2     = ws + OFF_G2;
  float* y      = ws + OFF_Y;
  float* consts = ws + OFF_CONSTS;
  float* Opart  = ws + OFF_OPART;
  float* lsp    = ws + OFF_LS;
  float* pdp    = ws + OFF_PD;
  float* out = (float*)d_out;

  prep_kernel<<<dim3(1), dim3(64), 0, stream>>>(lam, log_tau, logit_w, beta,
                                                out_scale, dp_scale, logk_scale,
                                                dt_logit, consts);
  zero_kernel<<<dim3(512), dim3(256), 0, stream>>>((float4*)Opart, NZERO4);
  gemm_abT_bf16<<<dim3(48, 16), dim3(128), 0, stream>>>(x, W_qkvg, qkvg, 1024, 3072, 768);
  pack_kernel<<<dim3(16, 12), dim3(256), 0, stream>>>(qkvg, g_norm_w, qhT, khT, ghT, g2);
  flash_kernel<<<dim3(144, 12), dim3(256), 0, stream>>>(qhT, khT, ghT, g2, qkvg, consts,
                                                        Opart, lsp, pdp);
  finalize_kernel<<<dim3(64, 12), dim3(256), 0, stream>>>(Opart, lsp, pdp, qkvg, consts, y);
  gemm_abT_bf16<<<dim3(12, 16), dim3(128), 0, stream>>>(y, W_out, out, 1024, 768, 768);
}

// Round 5
// 192.637 us; speedup vs baseline: 25.7781x; 1.3758x over previous
//
#include <hip/hip_runtime.h>
#include <math.h>

#define TSEQ 1024
#define CD   768
#define HN   12
#define DD   64

// workspace float offsets
#define OFF_QKVG   0          // 1024*3072 fp32
#define OFF_QH     3145728    // 12*1024*64 bf16 = 393216 floats
#define OFF_KH     3538944
#define OFF_GH     3932160
#define OFF_VHT    4325376    // 12*64*1024 bf16 (d-major)
#define OFF_G2     4718592    // 12*1024
#define OFF_Y      4730880    // 1024*768
#define OFF_CONSTS 5517312    // 12*24 + 1, pad 512
#define OFF_OPART  5517824    // 12*1024*64
#define OFF_LS     6304256    // 12*1024
#define OFF_PD     6316544    // 12*1024
#define NZERO4     199680     // (786432+12288)/4 : Opart+lsp

typedef __bf16 bf16x8 __attribute__((ext_vector_type(8)));
typedef float  f32x4  __attribute__((ext_vector_type(4)));
typedef unsigned short u16x8 __attribute__((ext_vector_type(8)));

__device__ inline unsigned short f2bf(float f) {
  unsigned int u = __float_as_uint(f);
  return (unsigned short)((u + 0x7fffu + ((u >> 16) & 1u)) >> 16);  // RNE
}

// consts per head (stride 24): [0]=lam*dp_scale/6.4, [1]=(1-lam)*logk_scale,
// [2]=clip(beta)/2, [3]=out_scale, [4..11]=1/(4*tau), [12..19]=log2(w+1e-12),
// [20]=ntt (1 if uniform tau & w, else 8). alpha at [288].

__global__ __launch_bounds__(64) void prep_kernel(
    const float* __restrict__ lam_p, const float* __restrict__ log_tau,
    const float* __restrict__ logit_w, const float* __restrict__ beta,
    const float* __restrict__ out_scale, const float* __restrict__ dp_scale,
    const float* __restrict__ logk_scale, const float* __restrict__ dt_logit,
    float* __restrict__ consts) {
  int h = threadIdx.x;
  if (h == 0) {
    float dt = 1.0f / (1.0f + __expf(-dt_logit[0]));
    consts[288] = 0.1f * dt;  // ESR_ALPHA * dt
  }
  if (h < HN) {
    float lam = lam_p[0];
    float* c = consts + h * 24;
    c[0] = lam * dp_scale[h] * (1.0f / 6.4f);  // sqrt(64)*0.8 = 6.4
    c[1] = (1.0f - lam) * logk_scale[h];
    float b = fminf(fmaxf(beta[h], 0.5f), 2.5f);
    c[2] = 0.5f * b;
    c[3] = out_scale[h];
    float m = -1e30f;
    float lw[8];
    bool uni = true;
    for (int t = 0; t < 8; t++) {
      lw[t] = logit_w[h * 8 + t];
      m = fmaxf(m, lw[t]);
      if (log_tau[h * 8 + t] != log_tau[h * 8] || lw[t] != lw[0]) uni = false;
    }
    float s = 0.f;
    float e[8];
    for (int t = 0; t < 8; t++) { e[t] = __expf(lw[t] - m); s += e[t]; }
    for (int t = 0; t < 8; t++) {
      float w = e[t] / s;
      c[12 + t] = log2f(w + 1e-12f);
      float tau = fmaxf(__expf(log_tau[h * 8 + t]), 1e-6f);
      c[4 + t] = 1.0f / (4.0f * tau);
    }
    c[20] = uni ? 1.0f : 8.0f;
  }
}

__global__ __launch_bounds__(256) void zero_kernel(float4* __restrict__ p, int n4) {
  int i = blockIdx.x * 256 + threadIdx.x;
  for (; i < n4; i += gridDim.x * 256) p[i] = make_float4(0.f, 0.f, 0.f, 0.f);
}

// C[M][N] = A[M][K] @ B[N][K]^T, fp32 in/out, bf16 MFMA inside. (verified R4)
__global__ __launch_bounds__(128) void gemm_abT_bf16(
    const float* __restrict__ A, const float* __restrict__ B,
    float* __restrict__ Cm, int M, int N, int K) {
  __shared__ __align__(16) unsigned short As[64 * 40];
  __shared__ __align__(16) unsigned short Bs[64 * 40];
  int t = threadIdx.x;
  int lane = t & 63, w = t >> 6;
  int quad = lane >> 4, col = lane & 15;
  int n0 = blockIdx.x * 64, m0 = blockIdx.y * 64;

  f32x4 acc[2][4] = {};

  for (int k0 = 0; k0 < K; k0 += 32) {
    __syncthreads();
#pragma unroll 4
    for (int rep = 0; rep < 8; rep++) {
      int pidx = rep * 128 + t;
      int r = pidx >> 4, kp = pidx & 15;
      float2 a2 = *(const float2*)&A[(size_t)(m0 + r) * K + k0 + 2 * kp];
      float2 b2 = *(const float2*)&B[(size_t)(n0 + r) * K + k0 + 2 * kp];
      *(unsigned int*)&As[r * 40 + 2 * kp] =
          (unsigned int)f2bf(a2.x) | ((unsigned int)f2bf(a2.y) << 16);
      *(unsigned int*)&Bs[r * 40 + 2 * kp] =
          (unsigned int)f2bf(b2.x) | ((unsigned int)f2bf(b2.y) << 16);
    }
    __syncthreads();

    bf16x8 af[2], bfv[4];
#pragma unroll
    for (int mi = 0; mi < 2; mi++)
      af[mi] = *(const bf16x8*)&As[(32 * w + mi * 16 + col) * 40 + quad * 8];
#pragma unroll
    for (int ni = 0; ni < 4; ni++)
      bfv[ni] = *(const bf16x8*)&Bs[(ni * 16 + col) * 40 + quad * 8];
#pragma unroll
    for (int mi = 0; mi < 2; mi++)
#pragma unroll
      for (int ni = 0; ni < 4; ni++)
        acc[mi][ni] = __builtin_amdgcn_mfma_f32_16x16x32_bf16(
            af[mi], bfv[ni], acc[mi][ni], 0, 0, 0);
  }

#pragma unroll
  for (int mi = 0; mi < 2; mi++)
#pragma unroll
    for (int ni = 0; ni < 4; ni++)
#pragma unroll
      for (int reg = 0; reg < 4; reg++) {
        int row = m0 + 32 * w + mi * 16 + quad * 4 + reg;
        Cm[(size_t)row * N + n0 + ni * 16 + col] = acc[mi][ni][reg];
      }
}

// Head-split + bf16 convert: qh/kh/gh row-major [H][T][D], vhT d-major [H][D][T].
// g rmsnormed; g2 computed from the bf16-ROUNDED g (consistency: s_ii == 0).
__global__ __launch_bounds__(256) void pack_kernel(
    const float* __restrict__ qkvg, const float* __restrict__ g_norm_w,
    unsigned short* __restrict__ qh, unsigned short* __restrict__ kh,
    unsigned short* __restrict__ gh, unsigned short* __restrict__ vhT,
    float* __restrict__ g2) {
  int h = blockIdx.y;
  int t0 = blockIdx.x * 64;
  int t = threadIdx.x;
  __shared__ float tile[64][65];
  __shared__ float gw[64];
  __shared__ float part[64][4];
  __shared__ float rr[64];
  if (t < 64) gw[t] = g_norm_w[t];

  // Phase A: q,k direct convert (coalesced both sides)
#pragma unroll
  for (int rep = 0; rep < 2; rep++) {
    int idx = rep * 256 + t;
    int r = idx >> 3, c8 = (idx & 7) * 8;
    const float* sq = &qkvg[(size_t)(t0 + r) * 3072 + h * 64 + c8];
    const float* sk = sq + CD;
    u16x8 uq, uk;
#pragma unroll
    for (int j = 0; j < 8; j++) { uq[j] = f2bf(sq[j]); uk[j] = f2bf(sk[j]); }
    *(u16x8*)&qh[(size_t)(h * 1024 + t0 + r) * 64 + c8] = uq;
    *(u16x8*)&kh[(size_t)(h * 1024 + t0 + r) * 64 + c8] = uk;
  }

  // Phase B: g rmsnorm -> gh bf16, g2 from rounded values
#pragma unroll 4
  for (int rep = 0; rep < 16; rep++) {
    int idx = rep * 256 + t;
    int r = idx >> 6, d = idx & 63;
    tile[r][d] = qkvg[(size_t)(t0 + r) * 3072 + 3 * CD + h * 64 + d];
  }
  __syncthreads();
  {
    int row = t >> 2, seg = t & 3;
    float s1 = 0.f;
    for (int d = seg * 16; d < seg * 16 + 16; d++) { float g = tile[row][d]; s1 += g * g; }
    part[row][seg] = s1;
  }
  __syncthreads();
  if (t < 64)
    rr[t] = rsqrtf((part[t][0] + part[t][1] + part[t][2] + part[t][3]) * (1.f / 64.f) + 1e-6f);
  __syncthreads();
  {
    int row = t >> 2, seg = t & 3;
    float rv = rr[row];
    float s2 = 0.f;
    u16x8 ua, ub;
#pragma unroll
    for (int j = 0; j < 8; j++) {
      float v = tile[row][seg * 16 + j] * rv * gw[seg * 16 + j];
      unsigned short us = f2bf(v); ua[j] = us;
      float vb = __uint_as_float((unsigned)us << 16); s2 += vb * vb;
    }
#pragma unroll
    for (int j = 0; j < 8; j++) {
      float v = tile[row][seg * 16 + 8 + j] * rv * gw[seg * 16 + 8 + j];
      unsigned short us = f2bf(v); ub[j] = us;
      float vb = __uint_as_float((unsigned)us << 16); s2 += vb * vb;
    }
    *(u16x8*)&gh[(size_t)(h * 1024 + t0 + row) * 64 + seg * 16] = ua;
    *(u16x8*)&gh[(size_t)(h * 1024 + t0 + row) * 64 + seg * 16 + 8] = ub;
    part[row][seg] = s2;
  }
  __syncthreads();
  if (t < 64) g2[h * 1024 + t0 + t] = part[t][0] + part[t][1] + part[t][2] + part[t][3];

  // Phase C: v transpose -> vhT bf16 [d][t]
  __syncthreads();
#pragma unroll 4
  for (int rep = 0; rep < 16; rep++) {
    int idx = rep * 256 + t;
    int r = idx >> 6, d = idx & 63;
    tile[r][d] = qkvg[(size_t)(t0 + r) * 3072 + 2 * CD + h * 64 + d];
  }
  __syncthreads();
#pragma unroll
  for (int rep = 0; rep < 2; rep++) {
    int idx = rep * 256 + t;
    int d = idx >> 3, tc8 = (idx & 7) * 8;
    u16x8 u;
#pragma unroll
    for (int j = 0; j < 8; j++) u[j] = f2bf(tile[tc8 + j][d]);
    *(u16x8*)&vhT[(size_t)(h * 64 + d) * 1024 + t0 + tc8] = u;
  }
}

// MFMA flash: block = (head, i-tile of 32 rows, chunk of <=2 j-tiles of 64).
// QK^T, GG^T, PV on matrix cores; transcendental score block on VALU.
// Wave w: m-strip mi=w>>1 (16 rows), n-pair nb=2*(w&1).
__global__ __launch_bounds__(256, 3) void flash_kernel(
    const unsigned short* __restrict__ qh, const unsigned short* __restrict__ kh,
    const unsigned short* __restrict__ gh, const unsigned short* __restrict__ vhT,
    const float* __restrict__ g2, const float* __restrict__ consts,
    float* __restrict__ Opart, float* __restrict__ lsp, float* __restrict__ pdp) {
  int h = blockIdx.y;
  int uu = 143 - (int)blockIdx.x;  // heavy first
  int it = 0, rem = uu;
  for (it = 0; it < 32; ++it) {
    int njt_ = (it >> 1) + 1;
    int nc = (njt_ + 1) >> 1;
    if (rem < nc) break;
    rem -= nc;
  }
  int njt = (it >> 1) + 1;
  int jt0 = rem * 2;
  int jt1 = (jt0 + 2 < njt) ? (jt0 + 2) : njt;
  bool owns_diag = (jt1 == njt);
  int i0 = it * 32;
  int t = threadIdx.x;
  int lane = t & 63, w = t >> 6;
  int quad = lane >> 4, tx = lane & 15;
  int mi = w >> 1, nb = (w & 1) * 2;

  __shared__ __align__(16) unsigned short Qa[32 * 72];
  __shared__ __align__(16) unsigned short Ga[32 * 72];
  __shared__ __align__(16) unsigned short Ks[64 * 72];
  __shared__ __align__(16) unsigned short Gjs[64 * 72];
  __shared__ __align__(16) unsigned short Vt[64 * 72];
  __shared__ __align__(16) unsigned short psh[32 * 72];
  __shared__ float g2i[32], g2j[64], pdiag[32];

  const float* ch = consts + h * 24;
  float dpc2 = ch[0] * 1.44269504089f;
  float lkc = ch[1], bh2 = ch[2];
  int ntt = (int)ch[20];
  float i4t0 = ch[4];
  float lkb = lkc * bh2;
  float inv4tau[8], logw[8];
#pragma unroll
  for (int tt = 0; tt < 8; tt++) { inv4tau[tt] = ch[4 + tt]; logw[tt] = ch[12 + tt]; }

  // stage Q/G i-tiles (32x64 bf16 each): one 16B unit per thread
  {
    int r = t >> 3, c8 = (t & 7) * 8;
    *(u16x8*)&Qa[r * 72 + c8] = *(const u16x8*)&qh[(size_t)(h * 1024 + i0 + r) * 64 + c8];
    *(u16x8*)&Ga[r * 72 + c8] = *(const u16x8*)&gh[(size_t)(h * 1024 + i0 + r) * 64 + c8];
  }
  if (t < 32) { g2i[t] = g2[h * 1024 + i0 + t]; pdiag[t] = 0.f; }
  __syncthreads();

  // persistent A-frags for Q,G (rows mi*16+tx, k = ks*32+quad*8)
  bf16x8 aq[2], ag[2];
#pragma unroll
  for (int ks = 0; ks < 2; ks++) {
    aq[ks] = *(const bf16x8*)&Qa[(mi * 16 + tx) * 72 + ks * 32 + quad * 8];
    ag[ks] = *(const bf16x8*)&Ga[(mi * 16 + tx) * 72 + ks * 32 + quad * 8];
  }

  f32x4 Oc[2] = {};
  float rowacc[4] = {0.f, 0.f, 0.f, 0.f};

  for (int jt = jt0; jt < jt1; jt++) {
    int j0 = jt * 64;
    __syncthreads();
    {
      int r4 = t >> 2, cb = (t & 3) * 16;
      const unsigned short* kp = &kh[(size_t)(h * 1024 + j0 + r4) * 64 + cb];
      const unsigned short* gp = &gh[(size_t)(h * 1024 + j0 + r4) * 64 + cb];
      const unsigned short* vp = &vhT[(size_t)(h * 64 + r4) * 1024 + j0 + cb];
      *(u16x8*)&Ks[r4 * 72 + cb] = *(const u16x8*)kp;
      *(u16x8*)&Ks[r4 * 72 + cb + 8] = *(const u16x8*)(kp + 8);
      *(u16x8*)&Gjs[r4 * 72 + cb] = *(const u16x8*)gp;
      *(u16x8*)&Gjs[r4 * 72 + cb + 8] = *(const u16x8*)(gp + 8);
      *(u16x8*)&Vt[r4 * 72 + cb] = *(const u16x8*)vp;
      *(u16x8*)&Vt[r4 * 72 + cb + 8] = *(const u16x8*)(vp + 8);
    }
    if (t < 64) g2j[t] = g2[h * 1024 + j0 + t];
    __syncthreads();

    // QK^T and GG^T via MFMA
    f32x4 sqk[2] = {}, sgg[2] = {};
#pragma unroll
    for (int ni2 = 0; ni2 < 2; ni2++) {
#pragma unroll
      for (int ks = 0; ks < 2; ks++) {
        bf16x8 bk = *(const bf16x8*)&Ks[((nb + ni2) * 16 + tx) * 72 + ks * 32 + quad * 8];
        sqk[ni2] = __builtin_amdgcn_mfma_f32_16x16x32_bf16(aq[ks], bk, sqk[ni2], 0, 0, 0);
        bf16x8 bg = *(const bf16x8*)&Gjs[((nb + ni2) * 16 + tx) * 72 + ks * 32 + quad * 8];
        sgg[ni2] = __builtin_amdgcn_mfma_f32_16x16x32_bf16(ag[ks], bg, sgg[ni2], 0, 0, 0);
      }
    }

    // scores: C layout row = quad*4+reg, col = tx
    float rs[4] = {0.f, 0.f, 0.f, 0.f};
#pragma unroll
    for (int ni2 = 0; ni2 < 2; ni2++) {
      int colg = j0 + (nb + ni2) * 16 + tx;
      float g2jv = g2j[(nb + ni2) * 16 + tx];
#pragma unroll
      for (int reg = 0; reg < 4; reg++) {
        int rowl = mi * 16 + quad * 4 + reg;
        int gi = i0 + rowl;
        float s = fmaxf(g2i[rowl] + g2jv - 2.0f * sgg[ni2][reg], 0.0f);
        float lse2;
        if (ntt == 1) {
          lse2 = -bh2 * __builtin_amdgcn_logf(fmaf(s, i4t0, 1.0f));  // log2 of kernel
        } else {
          float se = 0.f;
#pragma unroll
          for (int tt = 0; tt < 8; tt++) {
            float lv = __builtin_amdgcn_logf(fmaf(s, inv4tau[tt], 1.0f));
            se += __builtin_amdgcn_exp2f(fmaf(-bh2, lv, logw[tt]));
          }
          lse2 = __builtin_amdgcn_logf(se + 1e-30f);
        }
        float b = fmaf(dpc2, sqk[ni2][reg], lkc * lse2);
        float p = (colg <= gi) ? __builtin_amdgcn_exp2f(b) : 0.0f;
        rs[reg] += p;
        psh[rowl * 72 + (nb + ni2) * 16 + tx] = f2bf(p);
        if (colg == gi) pdiag[rowl] = p;
      }
    }
#pragma unroll
    for (int reg = 0; reg < 4; reg++) {
#pragma unroll
      for (int m = 1; m < 16; m <<= 1) rs[reg] += __shfl_xor(rs[reg], m, 64);
      rowacc[reg] += rs[reg];
    }
    __syncthreads();

    // PV via MFMA: A = P (rows mi strip), B = V^T
    bf16x8 ap[2];
#pragma unroll
    for (int ks = 0; ks < 2; ks++)
      ap[ks] = *(const bf16x8*)&psh[(mi * 16 + tx) * 72 + ks * 32 + quad * 8];
#pragma unroll
    for (int nd2 = 0; nd2 < 2; nd2++) {
#pragma unroll
      for (int ks = 0; ks < 2; ks++) {
        bf16x8 bv = *(const bf16x8*)&Vt[((nb + nd2) * 16 + tx) * 72 + ks * 32 + quad * 8];
        Oc[nd2] = __builtin_amdgcn_mfma_f32_16x16x32_bf16(ap[ks], bv, Oc[nd2], 0, 0, 0);
      }
    }
  }
  __syncthreads();

  // flush partials
#pragma unroll
  for (int nd2 = 0; nd2 < 2; nd2++) {
#pragma unroll
    for (int reg = 0; reg < 4; reg++) {
      int row = i0 + mi * 16 + quad * 4 + reg;
      atomicAdd(&Opart[(size_t)(h * 1024 + row) * 64 + (nb + nd2) * 16 + tx], Oc[nd2][reg]);
    }
  }
  if (tx == 0) {
#pragma unroll
    for (int reg = 0; reg < 4; reg++)
      atomicAdd(&lsp[h * 1024 + i0 + mi * 16 + quad * 4 + reg], rowacc[reg]);
  }
  if (owns_diag && t < 32) pdp[h * 1024 + i0 + t] = pdiag[t];
}

// y_i = osc*(c1*(P@v)_i + c2*v_i) with c1,c2 from P_ii (analytic P_rev)
__global__ __launch_bounds__(256) void finalize_kernel(
    const float* __restrict__ Opart, const float* __restrict__ lsp,
    const float* __restrict__ pdp, const float* __restrict__ qkvg,
    const float* __restrict__ consts, float* __restrict__ y) {
  int h = blockIdx.y;
  int t = threadIdx.x;
  int rl = t >> 4, d4 = t & 15;
  int gi = blockIdx.x * 16 + rl;
  float alpha = consts[288];
  float osc = consts[h * 24 + 3];
  float l = fmaxf(lsp[h * TSEQ + gi], 1e-12f);
  float Pii = pdp[h * TSEQ + gi] / l;
  float inv1p = 1.0f / (1.0f + Pii);
  float c1 = (1.0f - alpha) + alpha * inv1p;
  float c2 = alpha * Pii * inv1p;
  float invl = 1.0f / l;
  float4 Ov = *(const float4*)&Opart[(size_t)(h * 1024 + gi) * 64 + 4 * d4];
  float4 vi = *(const float4*)&qkvg[(size_t)gi * 3072 + 2 * CD + h * 64 + 4 * d4];
  float4 o;
  o.x = osc * (c1 * Ov.x * invl + c2 * vi.x);
  o.y = osc * (c1 * Ov.y * invl + c2 * vi.y);
  o.z = osc * (c1 * Ov.z * invl + c2 * vi.z);
  o.w = osc * (c1 * Ov.w * invl + c2 * vi.w);
  *(float4*)&y[(size_t)gi * CD + h * 64 + 4 * d4] = o;
}

extern "C" void kernel_launch(void* const* d_in, const int* in_sizes, int n_in,
                              void* d_out, int out_size, void* d_ws, size_t ws_size,
                              hipStream_t stream) {
  (void)in_sizes; (void)n_in; (void)out_size; (void)ws_size;
  const float* x          = (const float*)d_in[0];
  const float* W_qkvg     = (const float*)d_in[1];
  const float* W_out      = (const float*)d_in[2];
  const float* lam        = (const float*)d_in[3];
  const float* log_tau    = (const float*)d_in[4];
  const float* logit_w    = (const float*)d_in[5];
  const float* beta       = (const float*)d_in[6];
  const float* out_scale  = (const float*)d_in[7];
  const float* dp_scale   = (const float*)d_in[8];
  const float* logk_scale = (const float*)d_in[9];
  const float* dt_logit   = (const float*)d_in[10];
  const float* g_norm_w   = (const float*)d_in[11];
  float* ws = (float*)d_ws;
  float* qkvg   = ws + OFF_QKVG;
  unsigned short* qh  = (unsigned short*)(ws + OFF_QH);
  unsigned short* kh  = (unsigned short*)(ws + OFF_KH);
  unsigned short* gh  = (unsigned short*)(ws + OFF_GH);
  unsigned short* vhT = (unsigned short*)(ws + OFF_VHT);
  float* g2     = ws + OFF_G2;
  float* y      = ws + OFF_Y;
  float* consts = ws + OFF_CONSTS;
  float* Opart  = ws + OFF_OPART;
  float* lsp    = ws + OFF_LS;
  float* pdp    = ws + OFF_PD;
  float* out = (float*)d_out;

  prep_kernel<<<dim3(1), dim3(64), 0, stream>>>(lam, log_tau, logit_w, beta,
                                                out_scale, dp_scale, logk_scale,
                                                dt_logit, consts);
  zero_kernel<<<dim3(512), dim3(256), 0, stream>>>((float4*)Opart, NZERO4);
  gemm_abT_bf16<<<dim3(48, 16), dim3(128), 0, stream>>>(x, W_qkvg, qkvg, 1024, 3072, 768);
  pack_kernel<<<dim3(16, 12), dim3(256), 0, stream>>>(qkvg, g_norm_w, qh, kh, gh, vhT, g2);
  flash_kernel<<<dim3(144, 12), dim3(256), 0, stream>>>(qh, kh, gh, vhT, g2, consts,
                                                        Opart, lsp, pdp);
  finalize_kernel<<<dim3(64, 12), dim3(256), 0, stream>>>(Opart, lsp, pdp, qkvg, consts, y);
  gemm_abT_bf16<<<dim3(12, 16), dim3(128), 0, stream>>>(y, W_out, out, 1024, 768, 768);
}

// Round 6
// 153.437 us; speedup vs baseline: 32.3638x; 1.2555x over previous
//
#include <hip/hip_runtime.h>
#include <math.h>

#define TSEQ 1024
#define CD   768
#define HN   12
#define DD   64

// workspace float offsets (compact; end ~29.8 MB)
#define OFF_QKVG   0          // 1024*3072 fp32
#define OFF_QH     3145728    // bf16 12*1024*64 -> 393216 floats
#define OFF_KH     3538944
#define OFF_GH     3932160
#define OFF_VHT    4325376
#define OFF_G2     4718592    // 12*1024
#define OFF_YB     4730880    // bf16 1024*768 -> 393216 floats
#define OFF_CONSTS 5124096    // 512
#define OFF_OPART  5124608    // 786432
#define OFF_LS     5911040    // 12288 (must follow OPART for zeroing)
#define OFF_PD     5923328    // 12288
#define OFF_XB     5935616    // bf16 1024*768  -> 393216 floats
#define OFF_WQB    6328832    // bf16 3072*768  -> 1179648 floats
#define OFF_WOB    7508480    // bf16 768*768   -> 294912 floats (end 7803392)
#define NZERO4     199680     // (786432+12288)/4 : Opart+lsp

#define N_XB  786432
#define N_WQB 2359296
#define N_WOB 589824

typedef __bf16 bf16x8 __attribute__((ext_vector_type(8)));
typedef float  f32x4  __attribute__((ext_vector_type(4)));
typedef unsigned short u16x8 __attribute__((ext_vector_type(8)));
typedef unsigned short u16x4 __attribute__((ext_vector_type(4)));

__device__ inline unsigned short f2bf(float f) {
  unsigned int u = __float_as_uint(f);
  return (unsigned short)((u + 0x7fffu + ((u >> 16) & 1u)) >> 16);  // RNE
}

// consts per head (stride 24): [0]=lam*dp_scale/6.4, [1]=(1-lam)*logk_scale,
// [2]=clip(beta)/2, [3]=out_scale, [4..11]=1/(4*tau), [12..19]=log2(w+1e-12),
// [20]=ntt (1 if uniform tau & w, else 8). alpha at [288].

__global__ __launch_bounds__(64) void prep_kernel(
    const float* __restrict__ lam_p, const float* __restrict__ log_tau,
    const float* __restrict__ logit_w, const float* __restrict__ beta,
    const float* __restrict__ out_scale, const float* __restrict__ dp_scale,
    const float* __restrict__ logk_scale, const float* __restrict__ dt_logit,
    float* __restrict__ consts) {
  int h = threadIdx.x;
  if (h == 0) {
    float dt = 1.0f / (1.0f + __expf(-dt_logit[0]));
    consts[288] = 0.1f * dt;  // ESR_ALPHA * dt
  }
  if (h < HN) {
    float lam = lam_p[0];
    float* c = consts + h * 24;
    c[0] = lam * dp_scale[h] * (1.0f / 6.4f);
    c[1] = (1.0f - lam) * logk_scale[h];
    float b = fminf(fmaxf(beta[h], 0.5f), 2.5f);
    c[2] = 0.5f * b;
    c[3] = out_scale[h];
    float m = -1e30f;
    float lw[8];
    bool uni = true;
    for (int t = 0; t < 8; t++) {
      lw[t] = logit_w[h * 8 + t];
      m = fmaxf(m, lw[t]);
      if (log_tau[h * 8 + t] != log_tau[h * 8] || lw[t] != lw[0]) uni = false;
    }
    float s = 0.f;
    float e[8];
    for (int t = 0; t < 8; t++) { e[t] = __expf(lw[t] - m); s += e[t]; }
    for (int t = 0; t < 8; t++) {
      float w = e[t] / s;
      c[12 + t] = log2f(w + 1e-12f);
      float tau = fmaxf(__expf(log_tau[h * 8 + t]), 1e-6f);
      c[4 + t] = 1.0f / (4.0f * tau);
    }
    c[20] = uni ? 1.0f : 8.0f;
  }
}

__global__ __launch_bounds__(256) void zero_kernel(float4* __restrict__ p, int n4) {
  int i = blockIdx.x * 256 + threadIdx.x;
  for (; i < n4; i += gridDim.x * 256) p[i] = make_float4(0.f, 0.f, 0.f, 0.f);
}

// fp32 -> bf16 bulk convert: x, W_qkvg, W_out in one pass (8 elems/thread)
__global__ __launch_bounds__(256) void convert_kernel(
    const float* __restrict__ x, const float* __restrict__ wq,
    const float* __restrict__ wo, unsigned short* __restrict__ xb,
    unsigned short* __restrict__ wqb, unsigned short* __restrict__ wob) {
  int i8 = (blockIdx.x * 256 + threadIdx.x) * 8;
  const float* src;
  unsigned short* dst;
  int off;
  if (i8 < N_XB) { src = x; dst = xb; off = i8; }
  else if (i8 < N_XB + N_WQB) { src = wq; dst = wqb; off = i8 - N_XB; }
  else if (i8 < N_XB + N_WQB + N_WOB) { src = wo; dst = wob; off = i8 - N_XB - N_WQB; }
  else return;
  float4 a = *(const float4*)&src[off];
  float4 b = *(const float4*)&src[off + 4];
  u16x8 u;
  u[0] = f2bf(a.x); u[1] = f2bf(a.y); u[2] = f2bf(a.z); u[3] = f2bf(a.w);
  u[4] = f2bf(b.x); u[5] = f2bf(b.y); u[6] = f2bf(b.z); u[7] = f2bf(b.w);
  *(u16x8*)&dst[off] = u;
}

// C[M][N] = A[M][K] @ B[N][K]^T, A,B bf16, C fp32.
// Block = 256 threads (4 waves); tile 128(M)x64(N); K-step 64.
// Wave w: rows 32w..32w+31 (2x4 grid of 16x16 MFMA tiles over 64 cols).
__global__ __launch_bounds__(256, 2) void gemm_bf16_abT(
    const unsigned short* __restrict__ A, const unsigned short* __restrict__ B,
    float* __restrict__ Cm, int M, int N, int K) {
  __shared__ __align__(16) unsigned short As[128 * 72];
  __shared__ __align__(16) unsigned short Bs[64 * 72];
  int t = threadIdx.x;
  int lane = t & 63, w = t >> 6;
  int quad = lane >> 4, tx = lane & 15;
  int n0 = blockIdx.x * 64, m0 = blockIdx.y * 128;

  f32x4 acc[2][4] = {};
  int r_ = t >> 3, c8 = (t & 7) * 8;

  for (int k0 = 0; k0 < K; k0 += 64) {
    __syncthreads();
#pragma unroll
    for (int rep = 0; rep < 4; rep++) {
      int r = rep * 32 + r_;
      *(u16x8*)&As[r * 72 + c8] = *(const u16x8*)&A[(size_t)(m0 + r) * K + k0 + c8];
    }
#pragma unroll
    for (int rep = 0; rep < 2; rep++) {
      int r = rep * 32 + r_;
      *(u16x8*)&Bs[r * 72 + c8] = *(const u16x8*)&B[(size_t)(n0 + r) * K + k0 + c8];
    }
    __syncthreads();

#pragma unroll
    for (int ks = 0; ks < 2; ks++) {
      bf16x8 af[2];
#pragma unroll
      for (int mi = 0; mi < 2; mi++)
        af[mi] = *(const bf16x8*)&As[(32 * w + mi * 16 + tx) * 72 + ks * 32 + quad * 8];
#pragma unroll
      for (int ni = 0; ni < 4; ni++) {
        bf16x8 bv = *(const bf16x8*)&Bs[(ni * 16 + tx) * 72 + ks * 32 + quad * 8];
#pragma unroll
        for (int mi = 0; mi < 2; mi++)
          acc[mi][ni] = __builtin_amdgcn_mfma_f32_16x16x32_bf16(af[mi], bv, acc[mi][ni], 0, 0, 0);
      }
    }
  }

#pragma unroll
  for (int mi = 0; mi < 2; mi++)
#pragma unroll
    for (int ni = 0; ni < 4; ni++)
#pragma unroll
      for (int reg = 0; reg < 4; reg++) {
        int row = m0 + 32 * w + mi * 16 + quad * 4 + reg;
        Cm[(size_t)row * N + n0 + ni * 16 + tx] = acc[mi][ni][reg];
      }
}

// Head-split + bf16 convert: qh/kh/gh row-major [H][T][D], vhT d-major [H][D][T].
// g rmsnormed; g2 computed from the bf16-ROUNDED g (consistency: s_ii == 0).
__global__ __launch_bounds__(256) void pack_kernel(
    const float* __restrict__ qkvg, const float* __restrict__ g_norm_w,
    unsigned short* __restrict__ qh, unsigned short* __restrict__ kh,
    unsigned short* __restrict__ gh, unsigned short* __restrict__ vhT,
    float* __restrict__ g2) {
  int h = blockIdx.y;
  int t0 = blockIdx.x * 64;
  int t = threadIdx.x;
  __shared__ float tile[64][65];
  __shared__ float gw[64];
  __shared__ float part[64][4];
  __shared__ float rr[64];
  if (t < 64) gw[t] = g_norm_w[t];

  // Phase A: q,k direct convert (coalesced both sides)
#pragma unroll
  for (int rep = 0; rep < 2; rep++) {
    int idx = rep * 256 + t;
    int r = idx >> 3, c8 = (idx & 7) * 8;
    const float* sq = &qkvg[(size_t)(t0 + r) * 3072 + h * 64 + c8];
    const float* sk = sq + CD;
    u16x8 uq, uk;
#pragma unroll
    for (int j = 0; j < 8; j++) { uq[j] = f2bf(sq[j]); uk[j] = f2bf(sk[j]); }
    *(u16x8*)&qh[(size_t)(h * 1024 + t0 + r) * 64 + c8] = uq;
    *(u16x8*)&kh[(size_t)(h * 1024 + t0 + r) * 64 + c8] = uk;
  }

  // Phase B: g rmsnorm -> gh bf16, g2 from rounded values
#pragma unroll 4
  for (int rep = 0; rep < 16; rep++) {
    int idx = rep * 256 + t;
    int r = idx >> 6, d = idx & 63;
    tile[r][d] = qkvg[(size_t)(t0 + r) * 3072 + 3 * CD + h * 64 + d];
  }
  __syncthreads();
  {
    int row = t >> 2, seg = t & 3;
    float s1 = 0.f;
    for (int d = seg * 16; d < seg * 16 + 16; d++) { float g = tile[row][d]; s1 += g * g; }
    part[row][seg] = s1;
  }
  __syncthreads();
  if (t < 64)
    rr[t] = rsqrtf((part[t][0] + part[t][1] + part[t][2] + part[t][3]) * (1.f / 64.f) + 1e-6f);
  __syncthreads();
  {
    int row = t >> 2, seg = t & 3;
    float rv = rr[row];
    float s2 = 0.f;
    u16x8 ua, ub;
#pragma unroll
    for (int j = 0; j < 8; j++) {
      float v = tile[row][seg * 16 + j] * rv * gw[seg * 16 + j];
      unsigned short us = f2bf(v); ua[j] = us;
      float vb = __uint_as_float((unsigned)us << 16); s2 += vb * vb;
    }
#pragma unroll
    for (int j = 0; j < 8; j++) {
      float v = tile[row][seg * 16 + 8 + j] * rv * gw[seg * 16 + 8 + j];
      unsigned short us = f2bf(v); ub[j] = us;
      float vb = __uint_as_float((unsigned)us << 16); s2 += vb * vb;
    }
    *(u16x8*)&gh[(size_t)(h * 1024 + t0 + row) * 64 + seg * 16] = ua;
    *(u16x8*)&gh[(size_t)(h * 1024 + t0 + row) * 64 + seg * 16 + 8] = ub;
    part[row][seg] = s2;
  }
  __syncthreads();
  if (t < 64) g2[h * 1024 + t0 + t] = part[t][0] + part[t][1] + part[t][2] + part[t][3];

  // Phase C: v transpose -> vhT bf16 [d][t]
  __syncthreads();
#pragma unroll 4
  for (int rep = 0; rep < 16; rep++) {
    int idx = rep * 256 + t;
    int r = idx >> 6, d = idx & 63;
    tile[r][d] = qkvg[(size_t)(t0 + r) * 3072 + 2 * CD + h * 64 + d];
  }
  __syncthreads();
#pragma unroll
  for (int rep = 0; rep < 2; rep++) {
    int idx = rep * 256 + t;
    int d = idx >> 3, tc8 = (idx & 7) * 8;
    u16x8 u;
#pragma unroll
    for (int j = 0; j < 8; j++) u[j] = f2bf(tile[tc8 + j][d]);
    *(u16x8*)&vhT[(size_t)(h * 64 + d) * 1024 + t0 + tc8] = u;
  }
}

// MFMA flash: block = (head, i-tile of 32 rows, chunk of <=2 j-tiles of 64).
__global__ __launch_bounds__(256, 3) void flash_kernel(
    const unsigned short* __restrict__ qh, const unsigned short* __restrict__ kh,
    const unsigned short* __restrict__ gh, const unsigned short* __restrict__ vhT,
    const float* __restrict__ g2, const float* __restrict__ consts,
    float* __restrict__ Opart, float* __restrict__ lsp, float* __restrict__ pdp) {
  int h = blockIdx.y;
  int uu = 143 - (int)blockIdx.x;  // heavy first
  int it = 0, rem = uu;
  for (it = 0; it < 32; ++it) {
    int njt_ = (it >> 1) + 1;
    int nc = (njt_ + 1) >> 1;
    if (rem < nc) break;
    rem -= nc;
  }
  int njt = (it >> 1) + 1;
  int jt0 = rem * 2;
  int jt1 = (jt0 + 2 < njt) ? (jt0 + 2) : njt;
  bool owns_diag = (jt1 == njt);
  int i0 = it * 32;
  int t = threadIdx.x;
  int lane = t & 63, w = t >> 6;
  int quad = lane >> 4, tx = lane & 15;
  int mi = w >> 1, nb = (w & 1) * 2;

  __shared__ __align__(16) unsigned short Qa[32 * 72];
  __shared__ __align__(16) unsigned short Ga[32 * 72];
  __shared__ __align__(16) unsigned short Ks[64 * 72];
  __shared__ __align__(16) unsigned short Gjs[64 * 72];
  __shared__ __align__(16) unsigned short Vt[64 * 72];
  __shared__ __align__(16) unsigned short psh[32 * 72];
  __shared__ float g2i[32], g2j[64], pdiag[32];

  const float* ch = consts + h * 24;
  float dpc2 = ch[0] * 1.44269504089f;
  float lkc = ch[1], bh2 = ch[2];
  int ntt = (int)ch[20];
  float i4t0 = ch[4];
  float inv4tau[8], logw[8];
#pragma unroll
  for (int tt = 0; tt < 8; tt++) { inv4tau[tt] = ch[4 + tt]; logw[tt] = ch[12 + tt]; }

  {
    int r = t >> 3, c8 = (t & 7) * 8;
    *(u16x8*)&Qa[r * 72 + c8] = *(const u16x8*)&qh[(size_t)(h * 1024 + i0 + r) * 64 + c8];
    *(u16x8*)&Ga[r * 72 + c8] = *(const u16x8*)&gh[(size_t)(h * 1024 + i0 + r) * 64 + c8];
  }
  if (t < 32) { g2i[t] = g2[h * 1024 + i0 + t]; pdiag[t] = 0.f; }
  __syncthreads();

  bf16x8 aq[2], ag[2];
#pragma unroll
  for (int ks = 0; ks < 2; ks++) {
    aq[ks] = *(const bf16x8*)&Qa[(mi * 16 + tx) * 72 + ks * 32 + quad * 8];
    ag[ks] = *(const bf16x8*)&Ga[(mi * 16 + tx) * 72 + ks * 32 + quad * 8];
  }

  f32x4 Oc[2] = {};
  float rowacc[4] = {0.f, 0.f, 0.f, 0.f};

  for (int jt = jt0; jt < jt1; jt++) {
    int j0 = jt * 64;
    __syncthreads();
    {
      int r4 = t >> 2, cb = (t & 3) * 16;
      const unsigned short* kp = &kh[(size_t)(h * 1024 + j0 + r4) * 64 + cb];
      const unsigned short* gp = &gh[(size_t)(h * 1024 + j0 + r4) * 64 + cb];
      const unsigned short* vp = &vhT[(size_t)(h * 64 + r4) * 1024 + j0 + cb];
      *(u16x8*)&Ks[r4 * 72 + cb] = *(const u16x8*)kp;
      *(u16x8*)&Ks[r4 * 72 + cb + 8] = *(const u16x8*)(kp + 8);
      *(u16x8*)&Gjs[r4 * 72 + cb] = *(const u16x8*)gp;
      *(u16x8*)&Gjs[r4 * 72 + cb + 8] = *(const u16x8*)(gp + 8);
      *(u16x8*)&Vt[r4 * 72 + cb] = *(const u16x8*)vp;
      *(u16x8*)&Vt[r4 * 72 + cb + 8] = *(const u16x8*)(vp + 8);
    }
    if (t < 64) g2j[t] = g2[h * 1024 + j0 + t];
    __syncthreads();

    f32x4 sqk[2] = {}, sgg[2] = {};
#pragma unroll
    for (int ni2 = 0; ni2 < 2; ni2++) {
#pragma unroll
      for (int ks = 0; ks < 2; ks++) {
        bf16x8 bk = *(const bf16x8*)&Ks[((nb + ni2) * 16 + tx) * 72 + ks * 32 + quad * 8];
        sqk[ni2] = __builtin_amdgcn_mfma_f32_16x16x32_bf16(aq[ks], bk, sqk[ni2], 0, 0, 0);
        bf16x8 bg = *(const bf16x8*)&Gjs[((nb + ni2) * 16 + tx) * 72 + ks * 32 + quad * 8];
        sgg[ni2] = __builtin_amdgcn_mfma_f32_16x16x32_bf16(ag[ks], bg, sgg[ni2], 0, 0, 0);
      }
    }

    float rs[4] = {0.f, 0.f, 0.f, 0.f};
#pragma unroll
    for (int ni2 = 0; ni2 < 2; ni2++) {
      int colg = j0 + (nb + ni2) * 16 + tx;
      float g2jv = g2j[(nb + ni2) * 16 + tx];
#pragma unroll
      for (int reg = 0; reg < 4; reg++) {
        int rowl = mi * 16 + quad * 4 + reg;
        int gi = i0 + rowl;
        float s = fmaxf(g2i[rowl] + g2jv - 2.0f * sgg[ni2][reg], 0.0f);
        float lse2;
        if (ntt == 1) {
          lse2 = -bh2 * __builtin_amdgcn_logf(fmaf(s, i4t0, 1.0f));
        } else {
          float se = 0.f;
#pragma unroll
          for (int tt = 0; tt < 8; tt++) {
            float lv = __builtin_amdgcn_logf(fmaf(s, inv4tau[tt], 1.0f));
            se += __builtin_amdgcn_exp2f(fmaf(-bh2, lv, logw[tt]));
          }
          lse2 = __builtin_amdgcn_logf(se + 1e-30f);
        }
        float b = fmaf(dpc2, sqk[ni2][reg], lkc * lse2);
        float p = (colg <= gi) ? __builtin_amdgcn_exp2f(b) : 0.0f;
        rs[reg] += p;
        psh[rowl * 72 + (nb + ni2) * 16 + tx] = f2bf(p);
        if (colg == gi) pdiag[rowl] = p;
      }
    }
#pragma unroll
    for (int reg = 0; reg < 4; reg++) {
#pragma unroll
      for (int m = 1; m < 16; m <<= 1) rs[reg] += __shfl_xor(rs[reg], m, 64);
      rowacc[reg] += rs[reg];
    }
    __syncthreads();

    bf16x8 ap[2];
#pragma unroll
    for (int ks = 0; ks < 2; ks++)
      ap[ks] = *(const bf16x8*)&psh[(mi * 16 + tx) * 72 + ks * 32 + quad * 8];
#pragma unroll
    for (int nd2 = 0; nd2 < 2; nd2++) {
#pragma unroll
      for (int ks = 0; ks < 2; ks++) {
        bf16x8 bv = *(const bf16x8*)&Vt[((nb + nd2) * 16 + tx) * 72 + ks * 32 + quad * 8];
        Oc[nd2] = __builtin_amdgcn_mfma_f32_16x16x32_bf16(ap[ks], bv, Oc[nd2], 0, 0, 0);
      }
    }
  }
  __syncthreads();

#pragma unroll
  for (int nd2 = 0; nd2 < 2; nd2++) {
#pragma unroll
    for (int reg = 0; reg < 4; reg++) {
      int row = i0 + mi * 16 + quad * 4 + reg;
      atomicAdd(&Opart[(size_t)(h * 1024 + row) * 64 + (nb + nd2) * 16 + tx], Oc[nd2][reg]);
    }
  }
  if (tx == 0) {
#pragma unroll
    for (int reg = 0; reg < 4; reg++)
      atomicAdd(&lsp[h * 1024 + i0 + mi * 16 + quad * 4 + reg], rowacc[reg]);
  }
  if (owns_diag && t < 32) pdp[h * 1024 + i0 + t] = pdiag[t];
}

// y_i = osc*(c1*(P@v)_i + c2*v_i); writes yb in bf16 for the out-GEMM.
__global__ __launch_bounds__(256) void finalize_kernel(
    const float* __restrict__ Opart, const float* __restrict__ lsp,
    const float* __restrict__ pdp, const float* __restrict__ qkvg,
    const float* __restrict__ consts, unsigned short* __restrict__ yb) {
  int h = blockIdx.y;
  int t = threadIdx.x;
  int rl = t >> 4, d4 = t & 15;
  int gi = blockIdx.x * 16 + rl;
  float alpha = consts[288];
  float osc = consts[h * 24 + 3];
  float l = fmaxf(lsp[h * TSEQ + gi], 1e-12f);
  float Pii = pdp[h * TSEQ + gi] / l;
  float inv1p = 1.0f / (1.0f + Pii);
  float c1 = (1.0f - alpha) + alpha * inv1p;
  float c2 = alpha * Pii * inv1p;
  float invl = 1.0f / l;
  float4 Ov = *(const float4*)&Opart[(size_t)(h * 1024 + gi) * 64 + 4 * d4];
  float4 vi = *(const float4*)&qkvg[(size_t)gi * 3072 + 2 * CD + h * 64 + 4 * d4];
  u16x4 o;
  o[0] = f2bf(osc * (c1 * Ov.x * invl + c2 * vi.x));
  o[1] = f2bf(osc * (c1 * Ov.y * invl + c2 * vi.y));
  o[2] = f2bf(osc * (c1 * Ov.z * invl + c2 * vi.z));
  o[3] = f2bf(osc * (c1 * Ov.w * invl + c2 * vi.w));
  *(u16x4*)&yb[(size_t)gi * CD + h * 64 + 4 * d4] = o;
}

extern "C" void kernel_launch(void* const* d_in, const int* in_sizes, int n_in,
                              void* d_out, int out_size, void* d_ws, size_t ws_size,
                              hipStream_t stream) {
  (void)in_sizes; (void)n_in; (void)out_size; (void)ws_size;
  const float* x          = (const float*)d_in[0];
  const float* W_qkvg     = (const float*)d_in[1];
  const float* W_out      = (const float*)d_in[2];
  const float* lam        = (const float*)d_in[3];
  const float* log_tau    = (const float*)d_in[4];
  const float* logit_w    = (const float*)d_in[5];
  const float* beta       = (const float*)d_in[6];
  const float* out_scale  = (const float*)d_in[7];
  const float* dp_scale   = (const float*)d_in[8];
  const float* logk_scale = (const float*)d_in[9];
  const float* dt_logit   = (const float*)d_in[10];
  const float* g_norm_w   = (const float*)d_in[11];
  float* ws = (float*)d_ws;
  float* qkvg   = ws + OFF_QKVG;
  unsigned short* qh  = (unsigned short*)(ws + OFF_QH);
  unsigned short* kh  = (unsigned short*)(ws + OFF_KH);
  unsigned short* gh  = (unsigned short*)(ws + OFF_GH);
  unsigned short* vhT = (unsigned short*)(ws + OFF_VHT);
  float* g2     = ws + OFF_G2;
  unsigned short* yb  = (unsigned short*)(ws + OFF_YB);
  float* consts = ws + OFF_CONSTS;
  float* Opart  = ws + OFF_OPART;
  float* lsp    = ws + OFF_LS;
  float* pdp    = ws + OFF_PD;
  unsigned short* xb  = (unsigned short*)(ws + OFF_XB);
  unsigned short* wqb = (unsigned short*)(ws + OFF_WQB);
  unsigned short* wob = (unsigned short*)(ws + OFF_WOB);
  float* out = (float*)d_out;

  prep_kernel<<<dim3(1), dim3(64), 0, stream>>>(lam, log_tau, logit_w, beta,
                                                out_scale, dp_scale, logk_scale,
                                                dt_logit, consts);
  zero_kernel<<<dim3(512), dim3(256), 0, stream>>>((float4*)Opart, NZERO4);
  convert_kernel<<<dim3((N_XB + N_WQB + N_WOB) / (256 * 8)), dim3(256), 0, stream>>>(
      x, W_qkvg, W_out, xb, wqb, wob);
  gemm_bf16_abT<<<dim3(48, 8), dim3(256), 0, stream>>>(xb, wqb, qkvg, 1024, 3072, 768);
  pack_kernel<<<dim3(16, 12), dim3(256), 0, stream>>>(qkvg, g_norm_w, qh, kh, gh, vhT, g2);
  flash_kernel<<<dim3(144, 12), dim3(256), 0, stream>>>(qh, kh, gh, vhT, g2, consts,
                                                        Opart, lsp, pdp);
  finalize_kernel<<<dim3(64, 12), dim3(256), 0, stream>>>(Opart, lsp, pdp, qkvg, consts, yb);
  gemm_bf16_abT<<<dim3(12, 8), dim3(256), 0, stream>>>(yb, wob, out, 1024, 768, 768);
}